// Round 7
// baseline (4537.052 us; speedup 1.0000x reference)
//
#include <hip/hip_runtime.h>
#include <math.h>

// Problem constants
#define B_SZ    4096
#define D_DIM   128
#define K_CODES 8192
#define RECON_N (4096*84*84)   // 28901376

// ============================ VQ argmin + losses ============================
// Exact numpy-f32 semantics (verified R2/R3): d2q = fl32(zz - 2r), r = sequential
// f32 FMA chain over d ascending, zz = numpy pairwise-8. Ties -> lowest index.
__global__ __attribute__((amdgpu_flat_work_group_size(1024,1024),
                          amdgpu_waves_per_eu(4,8)))
void vq_kernel(
    const float* __restrict__ z, const float* __restrict__ cb,
    int* __restrict__ idx_ws, float* __restrict__ out_idx_f,
    double* __restrict__ lpart)
{
  __shared__ float z_s[16][128];
  __shared__ float zz_s[16];
  __shared__ float redv[16][16];   // [wave][row]
  __shared__ int   redi[16][16];
  __shared__ int   win[16];
  __shared__ double wsum[16];
  const int t  = threadIdx.x;
  const int b0 = blockIdx.x * 16;

  for (int p = t; p < 2048; p += 1024) z_s[p >> 7][p & 127] = z[(size_t)b0*128 + p];
  __syncthreads();

  // numpy pairwise-8 emulation of (z*z).sum(axis=1); separate mul/add roundings
  if (t < 16) {
    #pragma clang fp contract(off)
    const float* a = z_s[t];
    float r8[8];
    #pragma unroll
    for (int j = 0; j < 8; j++) { float v = a[j]*a[j]; r8[j] = v; }
    for (int i = 8; i < 128; i += 8) {
      #pragma unroll
      for (int j = 0; j < 8; j++) { float v = a[i+j]*a[i+j]; r8[j] = r8[j] + v; }
    }
    zz_s[t] = ((r8[0]+r8[1]) + (r8[2]+r8[3])) + ((r8[4]+r8[5]) + (r8[6]+r8[7]));
  }
  __syncthreads();

  const int lane = t & 63, wv = t >> 6;
  float zzr[16];
  #pragma unroll
  for (int row = 0; row < 16; row++) zzr[row] = zz_s[row];

  float best[16]; int bid[16];
  #pragma unroll
  for (int row = 0; row < 16; row++) { best[row] = INFINITY; bid[row] = 0; }

  #pragma unroll 1
  for (int k = 0; k < 8; k++) {
    const int cg   = wv + (k << 4);        // 16 waves cover 128 groups of 64 codes
    const int code = (cg << 6) + lane;     // ascending in k for fixed lane
    const float* ep = cb + (size_t)code * 128;
    float r[16];
    #pragma unroll
    for (int row = 0; row < 16; row++) r[row] = 0.0f;
    #pragma unroll 1
    for (int d16 = 0; d16 < 8; d16++) {
      const float4 e0 = *(const float4*)(ep + d16*16 + 0);
      const float4 e1 = *(const float4*)(ep + d16*16 + 4);
      const float4 e2 = *(const float4*)(ep + d16*16 + 8);
      const float4 e3 = *(const float4*)(ep + d16*16 + 12);
      #pragma unroll
      for (int row = 0; row < 16; row++) {
        const float4 z0 = *(const float4*)(&z_s[row][d16*16 + 0]);   // uniform -> broadcast
        const float4 z1 = *(const float4*)(&z_s[row][d16*16 + 4]);
        const float4 z2 = *(const float4*)(&z_s[row][d16*16 + 8]);
        const float4 z3 = *(const float4*)(&z_s[row][d16*16 + 12]);
        float rr = r[row];
        // single dependent FMA chain, d ascending — identical to R3 (bit-exact)
        rr = fmaf(z0.x,e0.x,rr); rr = fmaf(z0.y,e0.y,rr); rr = fmaf(z0.z,e0.z,rr); rr = fmaf(z0.w,e0.w,rr);
        rr = fmaf(z1.x,e1.x,rr); rr = fmaf(z1.y,e1.y,rr); rr = fmaf(z1.z,e1.z,rr); rr = fmaf(z1.w,e1.w,rr);
        rr = fmaf(z2.x,e2.x,rr); rr = fmaf(z2.y,e2.y,rr); rr = fmaf(z2.z,e2.z,rr); rr = fmaf(z2.w,e2.w,rr);
        rr = fmaf(z3.x,e3.x,rr); rr = fmaf(z3.y,e3.y,rr); rr = fmaf(z3.z,e3.z,rr); rr = fmaf(z3.w,e3.w,rr);
        r[row] = rr;
      }
    }
    #pragma unroll
    for (int row = 0; row < 16; row++) {
      const float tt = fmaf(-2.0f, r[row], zzr[row]);  // fl32(zz - 2r), single rounding
      if (tt < best[row]) { best[row] = tt; bid[row] = code; }
    }
  }

  // cross-lane lex argmin per row (tie -> smaller index)
  #pragma unroll 1
  for (int row = 0; row < 16; row++) {
    float v = best[row]; int i = bid[row];
    #pragma unroll
    for (int m = 32; m; m >>= 1) {
      float v2 = __shfl_xor(v, m, 64);
      int   i2 = __shfl_xor(i, m, 64);
      if (v2 < v || (v2 == v && i2 < i)) { v = v2; i = i2; }
    }
    if (lane == 0) { redv[wv][row] = v; redi[wv][row] = i; }
  }
  __syncthreads();

  if (t < 16) {   // row t: reduce over 16 waves
    float v = redv[0][t]; int i = redi[0][t];
    #pragma unroll 1
    for (int w = 1; w < 16; w++) {
      float v2 = redv[w][t]; int i2 = redi[w][t];
      if (v2 < v || (v2 == v && i2 < i)) { v = v2; i = i2; }
    }
    win[t] = i;
    idx_ws[b0 + t] = i;
    out_idx_f[b0 + t] = (float)i;   // float out; exact for idx < 2^24
  }
  __syncthreads();

  // loss partial: sum (z - e_win)^2 over 16 rows (f64; threshold slack huge)
  double ls = 0.0;
  for (int p = t; p < 2048; p += 1024) {
    int r = p >> 7, d = p & 127;
    float diff = z_s[r][d] - cb[(size_t)win[r]*128 + d];
    ls = fma((double)diff, (double)diff, ls);
  }
  #pragma unroll
  for (int m = 32; m; m >>= 1) ls += __shfl_xor(ls, m, 64);
  if (lane == 0) wsum[wv] = ls;
  __syncthreads();
  if (t == 0) {
    double s = 0.0;
    for (int w = 0; w < 16; w++) s += wsum[w];
    lpart[blockIdx.x] = s;
  }
}

__global__ __launch_bounds__(256) void fin_kernel(const double* __restrict__ lpart,
                                                  float* __restrict__ out_loss)
{
  __shared__ double s[256];
  const int t = threadIdx.x;
  s[t] = lpart[t];
  __syncthreads();
  for (int off = 128; off; off >>= 1) {
    if (t < off) s[t] += s[t + off];
    __syncthreads();
  }
  if (t == 0) {
    float l = (float)(s[0] / (4096.0*128.0));
    out_loss[0] = l;   // codebook_loss
    out_loss[1] = l;   // commitment_loss (same value)
  }
}

// ===================== linear: x1[b,o] = cb[idx[b]] . lin_w[o] + lin_b[o] ====
__global__ __launch_bounds__(256) void linear_kernel(
    const float* __restrict__ cb, const int* __restrict__ idx,
    const float* __restrict__ lw, const float* __restrict__ lb,
    float* __restrict__ x1)
{
  __shared__ float As[64][65];
  __shared__ float Bs[64][65];
  __shared__ int idx_s[64];
  const int t  = threadIdx.x;
  const int b0 = blockIdx.x * 64, n0 = blockIdx.y * 64;
  if (t < 64) idx_s[t] = idx[b0 + t];
  float acc[4][4] = {{0.f}};
  const int tr = (t >> 4)*4, tc = (t & 15)*4;
  for (int d0 = 0; d0 < 128; d0 += 64) {
    __syncthreads();
    #pragma unroll
    for (int l = 0; l < 16; l++) {
      int flat = t + l*256;
      int r = flat >> 6, d = flat & 63;
      As[r][d] = cb[(size_t)idx_s[r]*128 + d0 + d];
      Bs[r][d] = lw[(size_t)(n0 + r)*128 + d0 + d];
    }
    __syncthreads();
    #pragma unroll 8
    for (int d = 0; d < 64; d++) {
      float a0 = As[tr+0][d], a1 = As[tr+1][d], a2 = As[tr+2][d], a3 = As[tr+3][d];
      float q0 = Bs[tc+0][d], q1 = Bs[tc+1][d], q2 = Bs[tc+2][d], q3 = Bs[tc+3][d];
      acc[0][0] = fmaf(a0,q0,acc[0][0]); acc[0][1] = fmaf(a0,q1,acc[0][1]);
      acc[0][2] = fmaf(a0,q2,acc[0][2]); acc[0][3] = fmaf(a0,q3,acc[0][3]);
      acc[1][0] = fmaf(a1,q0,acc[1][0]); acc[1][1] = fmaf(a1,q1,acc[1][1]);
      acc[1][2] = fmaf(a1,q2,acc[1][2]); acc[1][3] = fmaf(a1,q3,acc[1][3]);
      acc[2][0] = fmaf(a2,q0,acc[2][0]); acc[2][1] = fmaf(a2,q1,acc[2][1]);
      acc[2][2] = fmaf(a2,q2,acc[2][2]); acc[2][3] = fmaf(a2,q3,acc[2][3]);
      acc[3][0] = fmaf(a3,q0,acc[3][0]); acc[3][1] = fmaf(a3,q1,acc[3][1]);
      acc[3][2] = fmaf(a3,q2,acc[3][2]); acc[3][3] = fmaf(a3,q3,acc[3][3]);
    }
  }
  #pragma unroll
  for (int i = 0; i < 4; i++)
    #pragma unroll
    for (int j = 0; j < 4; j++)
      x1[(size_t)(b0 + tr + i)*3136 + n0 + tc + j] = acc[i][j] + lb[n0 + tc + j];
}

// ========== decoder_a: conv1 + conv2, 2 img/block, SW-pipelined i-loops ======
// R7 (this session): occupancy is hard-capped ~14 waves/CU for every tested
// shape (R1/R5/R6), so the only remaining lever is per-wave stall removal.
// Arithmetic: FMA-issue is only ~32% of a block-round; the `unroll 1` i-loops
// expose ~200cy (L2 weights) + ~120cy (LDS rows) per iteration since the
// compiler won't prefetch across the loop-carried boundary. Fix: manual
// 2-deep software pipeline with two named register sets (rule-#20-safe, no
// dynamic indexing): load set B for i+1, FMA set A (i), load set A for i+2,
// FMA set B. FMA order per output is unchanged (i-ascending) -> bit-identical.
// Live regs: conv2 ~116, conv1 ~100 — under the 128 cap the 14-wave block
// forces. Structure otherwise identical to R4 (best: 1517us decoder_a).
#define DA_T 896
#define B1_CS 260            // channel stride (floats); %32==4 avoids epilogue-write pile-up
#define IMG_FL (64*B1_CS)    // floats per image's halo-plane set

// ---- conv1 pipeline macros (sets P/Q) ----
#define C1_LOADW(S, II) do { \
  const float* wp_ = w1 + ((((II) << 6) + c) << 4) + ky0*4; \
  const float4 A4_ = *(const float4*)(wp_); \
  const float4 B4_ = *(const float4*)(wp_ + 8); \
  wa##S[0]=A4_.x; wa##S[1]=A4_.y; wa##S[2]=A4_.z; wa##S[3]=A4_.w; \
  wb##S[0]=B4_.x; wb##S[1]=B4_.y; wb##S[2]=B4_.z; wb##S[3]=B4_.w; } while(0)

#define C1_LOADR(S, II) do { \
  if (v0) { \
    const float* xr_ = ximA + (II)*49 + iy0*7; \
    const float* xs_ = ximB + (II)*49 + iy0*7; \
    _Pragma("unroll") for (int j_ = 0; j_ < 7; j_++) { r0a##S[j_] = xr_[j_]; r0b##S[j_] = xs_[j_]; } \
  } else { \
    _Pragma("unroll") for (int j_ = 0; j_ < 7; j_++) { r0a##S[j_] = 0.0f; r0b##S[j_] = 0.0f; } \
  } \
  if (v1) { \
    const float* xr_ = ximA + (II)*49 + iy1*7; \
    const float* xs_ = ximB + (II)*49 + iy1*7; \
    _Pragma("unroll") for (int j_ = 0; j_ < 7; j_++) { r1a##S[j_] = xr_[j_]; r1b##S[j_] = xs_[j_]; } \
  } else { \
    _Pragma("unroll") for (int j_ = 0; j_ < 7; j_++) { r1a##S[j_] = 0.0f; r1b##S[j_] = 0.0f; } \
  } } while(0)

#define C1_FMAS(S) do { \
  _Pragma("unroll") for (int x_ = 0; x_ < 14; x_++) { \
    const int kxs_ = (x_ & 1) ? 0 : 1; \
    const int ix0_ = (x_ + 1 - kxs_) >> 1; \
    const int ix1_ = ix0_ - 1; \
    float s_ = accA[x_]; \
    if (ix0_ < 7)  { s_ = fmaf(r0a##S[ix0_], wa##S[kxs_],   s_); s_ = fmaf(r1a##S[ix0_], wb##S[kxs_],   s_); } \
    if (ix1_ >= 0) { s_ = fmaf(r0a##S[ix1_], wa##S[kxs_+2], s_); s_ = fmaf(r1a##S[ix1_], wb##S[kxs_+2], s_); } \
    accA[x_] = s_; } \
  _Pragma("unroll") for (int x_ = 0; x_ < 14; x_++) { \
    const int kxs_ = (x_ & 1) ? 0 : 1; \
    const int ix0_ = (x_ + 1 - kxs_) >> 1; \
    const int ix1_ = ix0_ - 1; \
    float s_ = accB[x_]; \
    if (ix0_ < 7)  { s_ = fmaf(r0b##S[ix0_], wa##S[kxs_],   s_); s_ = fmaf(r1b##S[ix0_], wb##S[kxs_],   s_); } \
    if (ix1_ >= 0) { s_ = fmaf(r0b##S[ix1_], wa##S[kxs_+2], s_); s_ = fmaf(r1b##S[ix1_], wb##S[kxs_+2], s_); } \
    accB[x_] = s_; } } while(0)

// ---- conv2 pipeline macros (sets A/B) ----
#define C2_LOADW(S, II) do { \
  const float* wp_ = w2 + ((((II) << 5) + c) << 4) + ky0*4; \
  const float4 A4_ = *(const float4*)(wp_); \
  const float4 B4_ = *(const float4*)(wp_ + 8); \
  wa##S[0]=A4_.x; wa##S[1]=A4_.y; wa##S[2]=A4_.z; wa##S[3]=A4_.w; \
  wb##S[0]=B4_.x; wb##S[1]=B4_.y; wb##S[2]=B4_.z; wb##S[3]=B4_.w; } while(0)

#define C2_LOADR(S, II) do { \
  const float* rp0_ = rbase0 + (II)*B1_CS; \
  const float* rp1_ = rbase1 + (II)*B1_CS; \
  _Pragma("unroll") for (int q_ = 0; q_ < 4; q_++) { \
    const float4 a4_ = *(const float4*)(rp0_ + q_*4); \
    r0##S[q_*4+0]=a4_.x; r0##S[q_*4+1]=a4_.y; r0##S[q_*4+2]=a4_.z; r0##S[q_*4+3]=a4_.w; } \
  _Pragma("unroll") for (int q_ = 0; q_ < 4; q_++) { \
    const float4 a4_ = *(const float4*)(rp1_ + q_*4); \
    r1##S[q_*4+0]=a4_.x; r1##S[q_*4+1]=a4_.y; r1##S[q_*4+2]=a4_.z; r1##S[q_*4+3]=a4_.w; } } while(0)

#define C2_FMAS(S) do { \
  _Pragma("unroll") for (int x_ = 0; x_ < 28; x_++) { \
    const int kxs_ = (x_ & 1) ? 0 : 1; \
    const int col_ = ((x_ + 1 - kxs_) >> 1) + 1; \
    float s_ = acc[x_]; \
    s_ = fmaf(r0##S[col_],   wa##S[kxs_],   s_); \
    s_ = fmaf(r1##S[col_],   wb##S[kxs_],   s_); \
    s_ = fmaf(r0##S[col_-1], wa##S[kxs_+2], s_); \
    s_ = fmaf(r1##S[col_-1], wb##S[kxs_+2], s_); \
    acc[x_] = s_; } } while(0)

__global__ __attribute__((amdgpu_flat_work_group_size(DA_T, DA_T),
                          amdgpu_waves_per_eu(4, 4)))
void decoder_a(
    const float* __restrict__ x1,
    const float* __restrict__ w1, const float* __restrict__ b1,
    const float* __restrict__ w2, const float* __restrict__ b2,
    float* __restrict__ a2, int b_off, int n_img)
{
  extern __shared__ float B1s[];   // 2*IMG_FL = 33280 floats = 133120 B
  const int tid = threadIdx.x;
  const int b   = blockIdx.x;
  const int iA  = 2*b;                    // local image index (chunk buffer)
  const bool hasB = (iA + 1) < n_img;     // block-uniform
  const int gA  = b_off + iA;             // global image index

  for (int p = tid; p < 2*IMG_FL; p += DA_T) B1s[p] = 0.0f;
  __syncthreads();

  // ---- conv1: (64,7,7) -> (64,14,14), relu. item = (c=tid&63, y=tid>>6) ----
  // Both images paired; weights+rows software-pipelined 2-deep (sets P/Q).
  {
    const int c = tid & 63, y = tid >> 6;
    const int ky0 = (y & 1) ? 0 : 1;
    const int iy0 = (y + 1 - ky0) >> 1;   // valid if <7
    const int iy1 = iy0 - 1;              // valid if >=0
    const bool v0 = (iy0 < 7), v1 = (iy1 >= 0);   // wave-uniform (y = wave idx)
    const float bias = b1[c];
    float accA[14], accB[14];
    #pragma unroll
    for (int x = 0; x < 14; x++) { accA[x] = bias; accB[x] = bias; }
    const float* ximA = x1 + (size_t)gA*3136;
    const float* ximB = hasB ? (ximA + 3136) : ximA;   // dup A when no B (stores guarded)

    float waP[4], wbP[4], waQ[4], wbQ[4];
    float r0aP[7], r1aP[7], r0bP[7], r1bP[7];
    float r0aQ[7], r1aQ[7], r0bQ[7], r1bQ[7];

    C1_LOADW(P, 0); C1_LOADR(P, 0);                 // prologue
    #pragma unroll 1
    for (int i = 0; i < 64; i += 2) {
      C1_LOADW(Q, i + 1); C1_LOADR(Q, i + 1);       // prefetch i+1
      C1_FMAS(P);                                   // compute i
      { const int i2 = (i + 2) & 63;                // wraps to 0 at tail (unused)
        C1_LOADW(P, i2); C1_LOADR(P, i2); }         // prefetch i+2
      C1_FMAS(Q);                                   // compute i+1
    }
    // write interior of halo planes: row y+1, cols 1..14
    float* oA = &B1s[c*B1_CS + (y + 1)*16 + 1];
    float* oB = oA + IMG_FL;
    #pragma unroll
    for (int x = 0; x < 14; x++) oA[x] = fmaxf(accA[x], 0.0f);
    #pragma unroll
    for (int x = 0; x < 14; x++) oB[x] = fmaxf(accB[x], 0.0f);
  }
  __syncthreads();

  // ---- conv2: (64,14,14) -> (32,28,28), relu. item = (c=tid&31, y=tid>>5) ----
  // Sequential per-image phases; weights+rows software-pipelined 2-deep.
  {
    const int c = tid & 31, y = tid >> 5;
    const int ky0 = (y & 1) ? 0 : 1;
    const int iy0 = (y + 1 - ky0) >> 1;     // 0..14
    const int row0 = iy0 + 1;               // halo row for ky0   (1..15)
    const int row1 = iy0;                   // halo row for ky0+2 (0..14)
    const float bias = b2[c];
    const int nimg = hasB ? 2 : 1;
    #pragma unroll 1
    for (int img = 0; img < nimg; img++) {
      const float* base   = &B1s[img*IMG_FL];
      const float* rbase0 = base + row0*16;
      const float* rbase1 = base + row1*16;
      float acc[28];
      #pragma unroll
      for (int x = 0; x < 28; x++) acc[x] = bias;

      float waA[4], wbA[4], waB[4], wbB[4];
      float r0A[16], r1A[16], r0B[16], r1B[16];

      C2_LOADW(A, 0); C2_LOADR(A, 0);               // prologue
      #pragma unroll 1
      for (int i = 0; i < 64; i += 2) {
        C2_LOADW(B, i + 1); C2_LOADR(B, i + 1);     // prefetch i+1
        C2_FMAS(A);                                 // compute i
        { const int i2 = (i + 2) & 63;              // wraps to 0 at tail (unused)
          C2_LOADW(A, i2); C2_LOADR(A, i2); }       // prefetch i+2
        C2_FMAS(B);                                 // compute i+1
      }
      // ---- epilogue: relu + store row (28 floats contiguous) ----
      float* st = a2 + (size_t)(iA + img)*25088 + c*784 + y*28;
      #pragma unroll
      for (int x = 0; x < 28; x++) acc[x] = fmaxf(acc[x], 0.0f);
      #pragma unroll
      for (int q = 0; q < 7; q++)
        *(float4*)(st + q*4) = make_float4(acc[q*4+0],acc[q*4+1],acc[q*4+2],acc[q*4+3]);
    }
  }
}

// ============ decoder_b: conv3 + bilinear resize 56->84 + tanh ==============
#define DB_T 896
__global__ __attribute__((amdgpu_flat_work_group_size(DB_T, DB_T)))
void decoder_b(
    const float* __restrict__ a2,
    const float* __restrict__ w3, const float* __restrict__ b3,
    float* __restrict__ out, int b_off)
{
  extern __shared__ float lds[];
  float* Cs  = lds;           // 25088 (a2 image, [c][y][x])
  float* Ds  = lds + 25088;   // 3136  (conv3 out, 56x56)
  float* W3s = lds + 28224;   // 512
  const int tid = threadIdx.x;
  const int b   = blockIdx.x;
  const int bg  = b + b_off;

  {
    const float4* src = (const float4*)(a2 + (size_t)b*25088);
    for (int p = tid; p < 6272; p += DB_T) ((float4*)Cs)[p] = src[p];
    for (int p = tid; p < 512; p += DB_T) W3s[p] = w3[p];
  }
  __syncthreads();

  if (tid < 784) {   // item = (y=tid/14 in 0..55, xq=tid%14), 4 px each
    const int y = tid / 14, xq = tid - y*14;
    const int x0 = xq * 4;
    const int ky0 = (y & 1) ? 0 : 1;
    const int iy0 = (y + 1 - ky0) >> 1;   // valid if <28
    const int iy1 = iy0 - 1;              // valid if >=0
    const bool v0 = (iy0 < 28), v1 = (iy1 >= 0);
    const int ixb = (x0 >> 1) - 1;        // input col for j=0
    float acc[4];
    const float bias = b3[0];
    #pragma unroll
    for (int x = 0; x < 4; x++) acc[x] = bias;
    #pragma unroll 1
    for (int i = 0; i < 32; i++) {
      const float* wr = &W3s[i*16 + ky0*4];
      float wa[4], wb[4];
      #pragma unroll
      for (int k = 0; k < 4; k++) { wa[k] = wr[k]; wb[k] = wr[8 + k]; }
      const float* Ci = &Cs[i*784];
      float r0[4], r1[4];
      #pragma unroll
      for (int j = 0; j < 4; j++) {
        const int ix = ixb + j;
        const bool vx = (ix >= 0) && (ix < 28);
        r0[j] = (v0 && vx) ? Ci[iy0*28 + ix] : 0.0f;
        r1[j] = (v1 && vx) ? Ci[iy1*28 + ix] : 0.0f;
      }
      #pragma unroll
      for (int xl = 0; xl < 4; xl++) {
        const int kxs = (xl & 1) ? 0 : 1;     // x0 even
        const int j = ((x0 + xl + 1 - kxs) >> 1) - ixb;   // 1..3
        float s = acc[xl];
        s = fmaf(r0[j],   wa[kxs],   s);
        s = fmaf(r1[j],   wb[kxs],   s);
        s = fmaf(r0[j-1], wa[kxs+2], s);
        s = fmaf(r1[j-1], wb[kxs+2], s);
        acc[xl] = s;
      }
    }
    *(float4*)(&Ds[y*56 + x0]) = make_float4(acc[0],acc[1],acc[2],acc[3]);
  }
  __syncthreads();

  // bilinear resize 56->84 (half-pixel, edge clamp == jax renorm) + tanh
  for (int p = tid; p < 84*84; p += DB_T) {
    const int oy = p / 84, ox = p - oy*84;
    const float sy = (oy + 0.5f)*(2.0f/3.0f) - 0.5f;
    const float sx = (ox + 0.5f)*(2.0f/3.0f) - 0.5f;
    const int y0 = (int)floorf(sy), x0i = (int)floorf(sx);
    const float fy = sy - (float)y0, fx = sx - (float)x0i;
    const int y0c = y0 < 0 ? 0 : y0, y1c = (y0 + 1 > 55) ? 55 : (y0 + 1);
    const int x0c = x0i < 0 ? 0 : x0i, x1c = (x0i + 1 > 55) ? 55 : (x0i + 1);
    const float v00 = Ds[y0c*56 + x0c], v01 = Ds[y0c*56 + x1c];
    const float v10 = Ds[y1c*56 + x0c], v11 = Ds[y1c*56 + x1c];
    const float v = (v00*(1.0f - fx) + v01*fx)*(1.0f - fy)
                  + (v10*(1.0f - fx) + v11*fx)*fy;
    out[(size_t)bg*7056 + p] = tanhf(v);
  }
}

// ================================ launch ====================================
extern "C" void kernel_launch(void* const* d_in, const int* in_sizes, int n_in,
                              void* d_out, int out_size, void* d_ws, size_t ws_size,
                              hipStream_t stream) {
  (void)in_sizes; (void)n_in; (void)out_size;
  const float* z  = (const float*)d_in[0];
  const float* cb = (const float*)d_in[1];
  const float* lw = (const float*)d_in[2];
  const float* lb = (const float*)d_in[3];
  const float* w1 = (const float*)d_in[4];
  const float* b1 = (const float*)d_in[5];
  const float* w2 = (const float*)d_in[6];
  const float* b2 = (const float*)d_in[7];
  const float* w3 = (const float*)d_in[8];
  const float* b3 = (const float*)d_in[9];

  float* out      = (float*)d_out;
  float* out_idx  = out + RECON_N;          // 4096 indices as float
  float* out_loss = out + RECON_N + 4096;   // 2 losses

  char*   ws     = (char*)d_ws;
  double* lpart  = (double*)ws;             // 256 doubles
  int*    idx_ws = (int*)(ws + 4096);       // 4096 ints
  float*  x1     = (float*)(ws + 32768);    // 4096*3136 floats (51.4 MB)
  const size_t a2_off = 32768 + (size_t)4096*3136*4;
  float*  a2     = (float*)(ws + a2_off);   // up to 4096*25088 floats (411 MB)

  // chunk the decoder if ws is too small for the full a2 buffer
  long long avail = (long long)ws_size - (long long)a2_off;
  int cap = (int)(avail / (25088*4));
  if (cap > 4096) cap = 4096;
  if (cap < 1) cap = 1;
  if (cap >= 2) cap &= ~1;   // even chunks so decoder_a blocks own full pairs

  vq_kernel<<<256, 1024, 0, stream>>>(z, cb, idx_ws, out_idx, lpart);
  fin_kernel<<<1, 256, 0, stream>>>(lpart, out_loss);
  linear_kernel<<<dim3(64, 49), 256, 0, stream>>>(cb, idx_ws, lw, lb, x1);

  const int da_lds = 2*IMG_FL*4;           // 133120 B (2 images)
  const int db_lds = (25088+3136+512)*4;   // 114944 B
  hipFuncSetAttribute((const void*)decoder_a,
                      hipFuncAttributeMaxDynamicSharedMemorySize, da_lds);
  hipFuncSetAttribute((const void*)decoder_b,
                      hipFuncAttributeMaxDynamicSharedMemorySize, db_lds);
  for (int b0 = 0; b0 < B_SZ; b0 += cap) {
    const int n = (B_SZ - b0 < cap) ? (B_SZ - b0) : cap;
    decoder_a<<<(n + 1)/2, DA_T, da_lds, stream>>>(x1, w1, b1, w2, b2, a2, b0, n);
    decoder_b<<<n, DB_T, db_lds, stream>>>(a2, w3, b3, out, b0);
  }
}

// Round 8
// 2778.053 us; speedup vs baseline: 1.6332x; 1.6332x over previous
//
#include <hip/hip_runtime.h>
#include <math.h>

// Problem constants
#define B_SZ    4096
#define D_DIM   128
#define K_CODES 8192
#define RECON_N (4096*84*84)   // 28901376

// ============================ VQ argmin + losses ============================
// Exact numpy-f32 semantics (verified R2/R3): d2q = fl32(zz - 2r), r = sequential
// f32 FMA chain over d ascending, zz = numpy pairwise-8. Ties -> lowest index.
__global__ __attribute__((amdgpu_flat_work_group_size(1024,1024),
                          amdgpu_waves_per_eu(4,8)))
void vq_kernel(
    const float* __restrict__ z, const float* __restrict__ cb,
    int* __restrict__ idx_ws, float* __restrict__ out_idx_f,
    double* __restrict__ lpart)
{
  __shared__ float z_s[16][128];
  __shared__ float zz_s[16];
  __shared__ float redv[16][16];   // [wave][row]
  __shared__ int   redi[16][16];
  __shared__ int   win[16];
  __shared__ double wsum[16];
  const int t  = threadIdx.x;
  const int b0 = blockIdx.x * 16;

  for (int p = t; p < 2048; p += 1024) z_s[p >> 7][p & 127] = z[(size_t)b0*128 + p];
  __syncthreads();

  // numpy pairwise-8 emulation of (z*z).sum(axis=1); separate mul/add roundings
  if (t < 16) {
    #pragma clang fp contract(off)
    const float* a = z_s[t];
    float r8[8];
    #pragma unroll
    for (int j = 0; j < 8; j++) { float v = a[j]*a[j]; r8[j] = v; }
    for (int i = 8; i < 128; i += 8) {
      #pragma unroll
      for (int j = 0; j < 8; j++) { float v = a[i+j]*a[i+j]; r8[j] = r8[j] + v; }
    }
    zz_s[t] = ((r8[0]+r8[1]) + (r8[2]+r8[3])) + ((r8[4]+r8[5]) + (r8[6]+r8[7]));
  }
  __syncthreads();

  const int lane = t & 63, wv = t >> 6;
  float zzr[16];
  #pragma unroll
  for (int row = 0; row < 16; row++) zzr[row] = zz_s[row];

  float best[16]; int bid[16];
  #pragma unroll
  for (int row = 0; row < 16; row++) { best[row] = INFINITY; bid[row] = 0; }

  #pragma unroll 1
  for (int k = 0; k < 8; k++) {
    const int cg   = wv + (k << 4);        // 16 waves cover 128 groups of 64 codes
    const int code = (cg << 6) + lane;     // ascending in k for fixed lane
    const float* ep = cb + (size_t)code * 128;
    float r[16];
    #pragma unroll
    for (int row = 0; row < 16; row++) r[row] = 0.0f;
    #pragma unroll 1
    for (int d16 = 0; d16 < 8; d16++) {
      const float4 e0 = *(const float4*)(ep + d16*16 + 0);
      const float4 e1 = *(const float4*)(ep + d16*16 + 4);
      const float4 e2 = *(const float4*)(ep + d16*16 + 8);
      const float4 e3 = *(const float4*)(ep + d16*16 + 12);
      #pragma unroll
      for (int row = 0; row < 16; row++) {
        const float4 z0 = *(const float4*)(&z_s[row][d16*16 + 0]);   // uniform -> broadcast
        const float4 z1 = *(const float4*)(&z_s[row][d16*16 + 4]);
        const float4 z2 = *(const float4*)(&z_s[row][d16*16 + 8]);
        const float4 z3 = *(const float4*)(&z_s[row][d16*16 + 12]);
        float rr = r[row];
        // single dependent FMA chain, d ascending — identical to R3 (bit-exact)
        rr = fmaf(z0.x,e0.x,rr); rr = fmaf(z0.y,e0.y,rr); rr = fmaf(z0.z,e0.z,rr); rr = fmaf(z0.w,e0.w,rr);
        rr = fmaf(z1.x,e1.x,rr); rr = fmaf(z1.y,e1.y,rr); rr = fmaf(z1.z,e1.z,rr); rr = fmaf(z1.w,e1.w,rr);
        rr = fmaf(z2.x,e2.x,rr); rr = fmaf(z2.y,e2.y,rr); rr = fmaf(z2.z,e2.z,rr); rr = fmaf(z2.w,e2.w,rr);
        rr = fmaf(z3.x,e3.x,rr); rr = fmaf(z3.y,e3.y,rr); rr = fmaf(z3.z,e3.z,rr); rr = fmaf(z3.w,e3.w,rr);
        r[row] = rr;
      }
    }
    #pragma unroll
    for (int row = 0; row < 16; row++) {
      const float tt = fmaf(-2.0f, r[row], zzr[row]);  // fl32(zz - 2r), single rounding
      if (tt < best[row]) { best[row] = tt; bid[row] = code; }
    }
  }

  // cross-lane lex argmin per row (tie -> smaller index)
  #pragma unroll 1
  for (int row = 0; row < 16; row++) {
    float v = best[row]; int i = bid[row];
    #pragma unroll
    for (int m = 32; m; m >>= 1) {
      float v2 = __shfl_xor(v, m, 64);
      int   i2 = __shfl_xor(i, m, 64);
      if (v2 < v || (v2 == v && i2 < i)) { v = v2; i = i2; }
    }
    if (lane == 0) { redv[wv][row] = v; redi[wv][row] = i; }
  }
  __syncthreads();

  if (t < 16) {   // row t: reduce over 16 waves
    float v = redv[0][t]; int i = redi[0][t];
    #pragma unroll 1
    for (int w = 1; w < 16; w++) {
      float v2 = redv[w][t]; int i2 = redi[w][t];
      if (v2 < v || (v2 == v && i2 < i)) { v = v2; i = i2; }
    }
    win[t] = i;
    idx_ws[b0 + t] = i;
    out_idx_f[b0 + t] = (float)i;   // float out; exact for idx < 2^24
  }
  __syncthreads();

  // loss partial: sum (z - e_win)^2 over 16 rows (f64; threshold slack huge)
  double ls = 0.0;
  for (int p = t; p < 2048; p += 1024) {
    int r = p >> 7, d = p & 127;
    float diff = z_s[r][d] - cb[(size_t)win[r]*128 + d];
    ls = fma((double)diff, (double)diff, ls);
  }
  #pragma unroll
  for (int m = 32; m; m >>= 1) ls += __shfl_xor(ls, m, 64);
  if (lane == 0) wsum[wv] = ls;
  __syncthreads();
  if (t == 0) {
    double s = 0.0;
    for (int w = 0; w < 16; w++) s += wsum[w];
    lpart[blockIdx.x] = s;
  }
}

__global__ __launch_bounds__(256) void fin_kernel(const double* __restrict__ lpart,
                                                  float* __restrict__ out_loss)
{
  __shared__ double s[256];
  const int t = threadIdx.x;
  s[t] = lpart[t];
  __syncthreads();
  for (int off = 128; off; off >>= 1) {
    if (t < off) s[t] += s[t + off];
    __syncthreads();
  }
  if (t == 0) {
    float l = (float)(s[0] / (4096.0*128.0));
    out_loss[0] = l;   // codebook_loss
    out_loss[1] = l;   // commitment_loss (same value)
  }
}

// ===================== linear: x1[b,o] = cb[idx[b]] . lin_w[o] + lin_b[o] ====
__global__ __launch_bounds__(256) void linear_kernel(
    const float* __restrict__ cb, const int* __restrict__ idx,
    const float* __restrict__ lw, const float* __restrict__ lb,
    float* __restrict__ x1)
{
  __shared__ float As[64][65];
  __shared__ float Bs[64][65];
  __shared__ int idx_s[64];
  const int t  = threadIdx.x;
  const int b0 = blockIdx.x * 64, n0 = blockIdx.y * 64;
  if (t < 64) idx_s[t] = idx[b0 + t];
  float acc[4][4] = {{0.f}};
  const int tr = (t >> 4)*4, tc = (t & 15)*4;
  for (int d0 = 0; d0 < 128; d0 += 64) {
    __syncthreads();
    #pragma unroll
    for (int l = 0; l < 16; l++) {
      int flat = t + l*256;
      int r = flat >> 6, d = flat & 63;
      As[r][d] = cb[(size_t)idx_s[r]*128 + d0 + d];
      Bs[r][d] = lw[(size_t)(n0 + r)*128 + d0 + d];
    }
    __syncthreads();
    #pragma unroll 8
    for (int d = 0; d < 64; d++) {
      float a0 = As[tr+0][d], a1 = As[tr+1][d], a2 = As[tr+2][d], a3 = As[tr+3][d];
      float q0 = Bs[tc+0][d], q1 = Bs[tc+1][d], q2 = Bs[tc+2][d], q3 = Bs[tc+3][d];
      acc[0][0] = fmaf(a0,q0,acc[0][0]); acc[0][1] = fmaf(a0,q1,acc[0][1]);
      acc[0][2] = fmaf(a0,q2,acc[0][2]); acc[0][3] = fmaf(a0,q3,acc[0][3]);
      acc[1][0] = fmaf(a1,q0,acc[1][0]); acc[1][1] = fmaf(a1,q1,acc[1][1]);
      acc[1][2] = fmaf(a1,q2,acc[1][2]); acc[1][3] = fmaf(a1,q3,acc[1][3]);
      acc[2][0] = fmaf(a2,q0,acc[2][0]); acc[2][1] = fmaf(a2,q1,acc[2][1]);
      acc[2][2] = fmaf(a2,q2,acc[2][2]); acc[2][3] = fmaf(a2,q3,acc[2][3]);
      acc[3][0] = fmaf(a3,q0,acc[3][0]); acc[3][1] = fmaf(a3,q1,acc[3][1]);
      acc[3][2] = fmaf(a3,q2,acc[3][2]); acc[3][3] = fmaf(a3,q3,acc[3][3]);
    }
  }
  #pragma unroll
  for (int i = 0; i < 4; i++)
    #pragma unroll
    for (int j = 0; j < 4; j++)
      x1[(size_t)(b0 + tr + i)*3136 + n0 + tc + j] = acc[i][j] + lb[n0 + tc + j];
}

// ===== decoder_a: conv1 + conv2, 2 img/block, WEIGHT-ONLY double-buffer ======
// R8 (this session): R7's full pipeline (2x row sets, ~123 live) spilled —
// allocator caps this kernel at ~64 VGPR and spills beyond (FETCH 34MB->3.5GB).
// Keep R4's structure (best point: 1517us) and prefetch ONLY the weights
// (+8 regs): unroll-by-2 with alternating weight sets P/Q — load w(i+1) before
// FMA(i), load w(i+2) before FMA(i+1). The ~200cy L2 weight latency hides
// under the 224cy FMA block; rows stay single-set (their shorter latency
// remains exposed). FMA chain per output unchanged -> bit-identical.
// Tripwire: FETCH_SIZE must stay ~34MB (no spill).
#define DA_T 896
#define B1_CS 260            // channel stride (floats); %32==4 avoids epilogue-write pile-up
#define IMG_FL (64*B1_CS)    // floats per image's halo-plane set

// ---- conv1: weight-set load (sets P/Q), rows single-set ----
#define C1_W(SET, II) do { \
  const float* wp_ = w1 + ((((II) << 6) + c) << 4) + ky0*4; \
  const float4 A4_ = *(const float4*)(wp_); \
  const float4 B4_ = *(const float4*)(wp_ + 8); \
  wa##SET[0]=A4_.x; wa##SET[1]=A4_.y; wa##SET[2]=A4_.z; wa##SET[3]=A4_.w; \
  wb##SET[0]=B4_.x; wb##SET[1]=B4_.y; wb##SET[2]=B4_.z; wb##SET[3]=B4_.w; } while(0)

#define C1_ROWS(II) do { \
  if (v0) { \
    const float* xr_ = ximA + (II)*49 + iy0*7; \
    const float* xs_ = ximB + (II)*49 + iy0*7; \
    _Pragma("unroll") for (int j_=0;j_<7;j_++){ r0A[j_]=xr_[j_]; r0B[j_]=xs_[j_]; } \
  } else { _Pragma("unroll") for (int j_=0;j_<7;j_++){ r0A[j_]=0.0f; r0B[j_]=0.0f; } } \
  if (v1) { \
    const float* xr_ = ximA + (II)*49 + iy1*7; \
    const float* xs_ = ximB + (II)*49 + iy1*7; \
    _Pragma("unroll") for (int j_=0;j_<7;j_++){ r1A[j_]=xr_[j_]; r1B[j_]=xs_[j_]; } \
  } else { _Pragma("unroll") for (int j_=0;j_<7;j_++){ r1A[j_]=0.0f; r1B[j_]=0.0f; } } } while(0)

#define C1_FMA(SET) do { \
  _Pragma("unroll") for (int x_=0;x_<14;x_++){ \
    const int kxs_=(x_&1)?0:1; const int ix0_=(x_+1-kxs_)>>1; const int ix1_=ix0_-1; \
    float s_=accA[x_]; \
    if (ix0_<7){ s_=fmaf(r0A[ix0_],wa##SET[kxs_],s_); s_=fmaf(r1A[ix0_],wb##SET[kxs_],s_);} \
    if (ix1_>=0){ s_=fmaf(r0A[ix1_],wa##SET[kxs_+2],s_); s_=fmaf(r1A[ix1_],wb##SET[kxs_+2],s_);} \
    accA[x_]=s_; } \
  _Pragma("unroll") for (int x_=0;x_<14;x_++){ \
    const int kxs_=(x_&1)?0:1; const int ix0_=(x_+1-kxs_)>>1; const int ix1_=ix0_-1; \
    float s_=accB[x_]; \
    if (ix0_<7){ s_=fmaf(r0B[ix0_],wa##SET[kxs_],s_); s_=fmaf(r1B[ix0_],wb##SET[kxs_],s_);} \
    if (ix1_>=0){ s_=fmaf(r0B[ix1_],wa##SET[kxs_+2],s_); s_=fmaf(r1B[ix1_],wb##SET[kxs_+2],s_);} \
    accB[x_]=s_; } } while(0)

// ---- conv2: weight-set load (sets P/Q), rows single-set ----
#define C2_W(SET, II) do { \
  const float* wp_ = w2 + ((((II) << 5) + c) << 4) + ky0*4; \
  const float4 A4_ = *(const float4*)(wp_); \
  const float4 B4_ = *(const float4*)(wp_ + 8); \
  wa##SET[0]=A4_.x; wa##SET[1]=A4_.y; wa##SET[2]=A4_.z; wa##SET[3]=A4_.w; \
  wb##SET[0]=B4_.x; wb##SET[1]=B4_.y; wb##SET[2]=B4_.z; wb##SET[3]=B4_.w; } while(0)

#define C2_ROWS(II) do { \
  const float* rp0_ = rbase0 + (II)*B1_CS; \
  const float* rp1_ = rbase1 + (II)*B1_CS; \
  _Pragma("unroll") for (int q_=0;q_<4;q_++){ \
    const float4 a4_ = *(const float4*)(rp0_ + q_*4); \
    r0[q_*4+0]=a4_.x; r0[q_*4+1]=a4_.y; r0[q_*4+2]=a4_.z; r0[q_*4+3]=a4_.w; } \
  _Pragma("unroll") for (int q_=0;q_<4;q_++){ \
    const float4 a4_ = *(const float4*)(rp1_ + q_*4); \
    r1[q_*4+0]=a4_.x; r1[q_*4+1]=a4_.y; r1[q_*4+2]=a4_.z; r1[q_*4+3]=a4_.w; } } while(0)

#define C2_FMA(SET) do { \
  _Pragma("unroll") for (int x_=0;x_<28;x_++){ \
    const int kxs_=(x_&1)?0:1; const int col_=((x_+1-kxs_)>>1)+1; \
    float s_=acc[x_]; \
    s_=fmaf(r0[col_],   wa##SET[kxs_],   s_); \
    s_=fmaf(r1[col_],   wb##SET[kxs_],   s_); \
    s_=fmaf(r0[col_-1], wa##SET[kxs_+2], s_); \
    s_=fmaf(r1[col_-1], wb##SET[kxs_+2], s_); \
    acc[x_]=s_; } } while(0)

__global__ __attribute__((amdgpu_flat_work_group_size(DA_T, DA_T),
                          amdgpu_waves_per_eu(4, 4)))
void decoder_a(
    const float* __restrict__ x1,
    const float* __restrict__ w1, const float* __restrict__ b1,
    const float* __restrict__ w2, const float* __restrict__ b2,
    float* __restrict__ a2, int b_off, int n_img)
{
  extern __shared__ float B1s[];   // 2*IMG_FL = 33280 floats = 133120 B
  const int tid = threadIdx.x;
  const int b   = blockIdx.x;
  const int iA  = 2*b;                    // local image index (chunk buffer)
  const bool hasB = (iA + 1) < n_img;     // block-uniform
  const int gA  = b_off + iA;             // global image index

  for (int p = tid; p < 2*IMG_FL; p += DA_T) B1s[p] = 0.0f;
  __syncthreads();

  // ---- conv1: (64,7,7) -> (64,14,14), relu. item = (c=tid&63, y=tid>>6) ----
  {
    const int c = tid & 63, y = tid >> 6;
    const int ky0 = (y & 1) ? 0 : 1;
    const int iy0 = (y + 1 - ky0) >> 1;   // valid if <7
    const int iy1 = iy0 - 1;              // valid if >=0
    const bool v0 = (iy0 < 7), v1 = (iy1 >= 0);   // wave-uniform (y = wave idx)
    const float bias = b1[c];
    float accA[14], accB[14];
    #pragma unroll
    for (int x = 0; x < 14; x++) { accA[x] = bias; accB[x] = bias; }
    const float* ximA = x1 + (size_t)gA*3136;
    const float* ximB = hasB ? (ximA + 3136) : ximA;   // dup A when no B (stores guarded)

    float waP[4], wbP[4], waQ[4], wbQ[4];
    float r0A[7], r1A[7], r0B[7], r1B[7];

    C1_W(P, 0);                                    // prologue
    #pragma unroll 1
    for (int i = 0; i < 64; i += 2) {
      C1_W(Q, i + 1);                              // prefetch weights i+1
      C1_ROWS(i);
      C1_FMA(P);                                   // compute i
      C1_W(P, (i + 2) & 63);                       // prefetch weights i+2 (wrap unused)
      C1_ROWS(i + 1);
      C1_FMA(Q);                                   // compute i+1
    }
    // write interior of halo planes: row y+1, cols 1..14
    float* oA = &B1s[c*B1_CS + (y + 1)*16 + 1];
    float* oB = oA + IMG_FL;
    #pragma unroll
    for (int x = 0; x < 14; x++) oA[x] = fmaxf(accA[x], 0.0f);
    #pragma unroll
    for (int x = 0; x < 14; x++) oB[x] = fmaxf(accB[x], 0.0f);
  }
  __syncthreads();

  // ---- conv2: (64,14,14) -> (32,28,28), relu. item = (c=tid&31, y=tid>>5) ----
  // Sequential per-image phases; weights double-buffered, rows single-set.
  {
    const int c = tid & 31, y = tid >> 5;
    const int ky0 = (y & 1) ? 0 : 1;
    const int iy0 = (y + 1 - ky0) >> 1;     // 0..14
    const int row0 = iy0 + 1;               // halo row for ky0   (1..15)
    const int row1 = iy0;                   // halo row for ky0+2 (0..14)
    const float bias = b2[c];
    const int nimg = hasB ? 2 : 1;
    #pragma unroll 1
    for (int img = 0; img < nimg; img++) {
      const float* base   = &B1s[img*IMG_FL];
      const float* rbase0 = base + row0*16;
      const float* rbase1 = base + row1*16;
      float acc[28];
      #pragma unroll
      for (int x = 0; x < 28; x++) acc[x] = bias;

      float waP[4], wbP[4], waQ[4], wbQ[4];
      float r0[16], r1[16];

      C2_W(P, 0);                                  // prologue
      #pragma unroll 1
      for (int i = 0; i < 64; i += 2) {
        C2_W(Q, i + 1);                            // prefetch weights i+1
        C2_ROWS(i);
        C2_FMA(P);                                 // compute i
        C2_W(P, (i + 2) & 63);                     // prefetch weights i+2 (wrap unused)
        C2_ROWS(i + 1);
        C2_FMA(Q);                                 // compute i+1
      }
      // ---- epilogue: relu + store row (28 floats contiguous) ----
      float* st = a2 + (size_t)(iA + img)*25088 + c*784 + y*28;
      #pragma unroll
      for (int x = 0; x < 28; x++) acc[x] = fmaxf(acc[x], 0.0f);
      #pragma unroll
      for (int q = 0; q < 7; q++)
        *(float4*)(st + q*4) = make_float4(acc[q*4+0],acc[q*4+1],acc[q*4+2],acc[q*4+3]);
    }
  }
}

// ============ decoder_b: conv3 + bilinear resize 56->84 + tanh ==============
#define DB_T 896
__global__ __attribute__((amdgpu_flat_work_group_size(DB_T, DB_T)))
void decoder_b(
    const float* __restrict__ a2,
    const float* __restrict__ w3, const float* __restrict__ b3,
    float* __restrict__ out, int b_off)
{
  extern __shared__ float lds[];
  float* Cs  = lds;           // 25088 (a2 image, [c][y][x])
  float* Ds  = lds + 25088;   // 3136  (conv3 out, 56x56)
  float* W3s = lds + 28224;   // 512
  const int tid = threadIdx.x;
  const int b   = blockIdx.x;
  const int bg  = b + b_off;

  {
    const float4* src = (const float4*)(a2 + (size_t)b*25088);
    for (int p = tid; p < 6272; p += DB_T) ((float4*)Cs)[p] = src[p];
    for (int p = tid; p < 512; p += DB_T) W3s[p] = w3[p];
  }
  __syncthreads();

  if (tid < 784) {   // item = (y=tid/14 in 0..55, xq=tid%14), 4 px each
    const int y = tid / 14, xq = tid - y*14;
    const int x0 = xq * 4;
    const int ky0 = (y & 1) ? 0 : 1;
    const int iy0 = (y + 1 - ky0) >> 1;   // valid if <28
    const int iy1 = iy0 - 1;              // valid if >=0
    const bool v0 = (iy0 < 28), v1 = (iy1 >= 0);
    const int ixb = (x0 >> 1) - 1;        // input col for j=0
    float acc[4];
    const float bias = b3[0];
    #pragma unroll
    for (int x = 0; x < 4; x++) acc[x] = bias;
    #pragma unroll 1
    for (int i = 0; i < 32; i++) {
      const float* wr = &W3s[i*16 + ky0*4];
      float wa[4], wb[4];
      #pragma unroll
      for (int k = 0; k < 4; k++) { wa[k] = wr[k]; wb[k] = wr[8 + k]; }
      const float* Ci = &Cs[i*784];
      float r0[4], r1[4];
      #pragma unroll
      for (int j = 0; j < 4; j++) {
        const int ix = ixb + j;
        const bool vx = (ix >= 0) && (ix < 28);
        r0[j] = (v0 && vx) ? Ci[iy0*28 + ix] : 0.0f;
        r1[j] = (v1 && vx) ? Ci[iy1*28 + ix] : 0.0f;
      }
      #pragma unroll
      for (int xl = 0; xl < 4; xl++) {
        const int kxs = (xl & 1) ? 0 : 1;     // x0 even
        const int j = ((x0 + xl + 1 - kxs) >> 1) - ixb;   // 1..3
        float s = acc[xl];
        s = fmaf(r0[j],   wa[kxs],   s);
        s = fmaf(r1[j],   wb[kxs],   s);
        s = fmaf(r0[j-1], wa[kxs+2], s);
        s = fmaf(r1[j-1], wb[kxs+2], s);
        acc[xl] = s;
      }
    }
    *(float4*)(&Ds[y*56 + x0]) = make_float4(acc[0],acc[1],acc[2],acc[3]);
  }
  __syncthreads();

  // bilinear resize 56->84 (half-pixel, edge clamp == jax renorm) + tanh
  for (int p = tid; p < 84*84; p += DB_T) {
    const int oy = p / 84, ox = p - oy*84;
    const float sy = (oy + 0.5f)*(2.0f/3.0f) - 0.5f;
    const float sx = (ox + 0.5f)*(2.0f/3.0f) - 0.5f;
    const int y0 = (int)floorf(sy), x0i = (int)floorf(sx);
    const float fy = sy - (float)y0, fx = sx - (float)x0i;
    const int y0c = y0 < 0 ? 0 : y0, y1c = (y0 + 1 > 55) ? 55 : (y0 + 1);
    const int x0c = x0i < 0 ? 0 : x0i, x1c = (x0i + 1 > 55) ? 55 : (x0i + 1);
    const float v00 = Ds[y0c*56 + x0c], v01 = Ds[y0c*56 + x1c];
    const float v10 = Ds[y1c*56 + x0c], v11 = Ds[y1c*56 + x1c];
    const float v = (v00*(1.0f - fx) + v01*fx)*(1.0f - fy)
                  + (v10*(1.0f - fx) + v11*fx)*fy;
    out[(size_t)bg*7056 + p] = tanhf(v);
  }
}

// ================================ launch ====================================
extern "C" void kernel_launch(void* const* d_in, const int* in_sizes, int n_in,
                              void* d_out, int out_size, void* d_ws, size_t ws_size,
                              hipStream_t stream) {
  (void)in_sizes; (void)n_in; (void)out_size;
  const float* z  = (const float*)d_in[0];
  const float* cb = (const float*)d_in[1];
  const float* lw = (const float*)d_in[2];
  const float* lb = (const float*)d_in[3];
  const float* w1 = (const float*)d_in[4];
  const float* b1 = (const float*)d_in[5];
  const float* w2 = (const float*)d_in[6];
  const float* b2 = (const float*)d_in[7];
  const float* w3 = (const float*)d_in[8];
  const float* b3 = (const float*)d_in[9];

  float* out      = (float*)d_out;
  float* out_idx  = out + RECON_N;          // 4096 indices as float
  float* out_loss = out + RECON_N + 4096;   // 2 losses

  char*   ws     = (char*)d_ws;
  double* lpart  = (double*)ws;             // 256 doubles
  int*    idx_ws = (int*)(ws + 4096);       // 4096 ints
  float*  x1     = (float*)(ws + 32768);    // 4096*3136 floats (51.4 MB)
  const size_t a2_off = 32768 + (size_t)4096*3136*4;
  float*  a2     = (float*)(ws + a2_off);   // up to 4096*25088 floats (411 MB)

  // chunk the decoder if ws is too small for the full a2 buffer
  long long avail = (long long)ws_size - (long long)a2_off;
  int cap = (int)(avail / (25088*4));
  if (cap > 4096) cap = 4096;
  if (cap < 1) cap = 1;
  if (cap >= 2) cap &= ~1;   // even chunks so decoder_a blocks own full pairs

  vq_kernel<<<256, 1024, 0, stream>>>(z, cb, idx_ws, out_idx, lpart);
  fin_kernel<<<1, 256, 0, stream>>>(lpart, out_loss);
  linear_kernel<<<dim3(64, 49), 256, 0, stream>>>(cb, idx_ws, lw, lb, x1);

  const int da_lds = 2*IMG_FL*4;           // 133120 B (2 images)
  const int db_lds = (25088+3136+512)*4;   // 114944 B
  hipFuncSetAttribute((const void*)decoder_a,
                      hipFuncAttributeMaxDynamicSharedMemorySize, da_lds);
  hipFuncSetAttribute((const void*)decoder_b,
                      hipFuncAttributeMaxDynamicSharedMemorySize, db_lds);
  for (int b0 = 0; b0 < B_SZ; b0 += cap) {
    const int n = (B_SZ - b0 < cap) ? (B_SZ - b0) : cap;
    decoder_a<<<(n + 1)/2, DA_T, da_lds, stream>>>(x1, w1, b1, w2, b2, a2, b0, n);
    decoder_b<<<n, DB_T, db_lds, stream>>>(a2, w3, b3, out, b0);
  }
}

// Round 9
// 2278.198 us; speedup vs baseline: 1.9915x; 1.2194x over previous
//
#include <hip/hip_runtime.h>
#include <math.h>

// Problem constants
#define B_SZ    4096
#define D_DIM   128
#define K_CODES 8192
#define RECON_N (4096*84*84)   // 28901376

// ============================ VQ argmin + losses ============================
// Exact numpy-f32 semantics (verified R2/R3): d2q = fl32(zz - 2r), r = sequential
// f32 FMA chain over d ascending, zz = numpy pairwise-8. Ties -> lowest index.
__global__ __attribute__((amdgpu_flat_work_group_size(1024,1024),
                          amdgpu_waves_per_eu(4,8)))
void vq_kernel(
    const float* __restrict__ z, const float* __restrict__ cb,
    int* __restrict__ idx_ws, float* __restrict__ out_idx_f,
    double* __restrict__ lpart)
{
  __shared__ float z_s[16][128];
  __shared__ float zz_s[16];
  __shared__ float redv[16][16];   // [wave][row]
  __shared__ int   redi[16][16];
  __shared__ int   win[16];
  __shared__ double wsum[16];
  const int t  = threadIdx.x;
  const int b0 = blockIdx.x * 16;

  for (int p = t; p < 2048; p += 1024) z_s[p >> 7][p & 127] = z[(size_t)b0*128 + p];
  __syncthreads();

  // numpy pairwise-8 emulation of (z*z).sum(axis=1); separate mul/add roundings
  if (t < 16) {
    #pragma clang fp contract(off)
    const float* a = z_s[t];
    float r8[8];
    #pragma unroll
    for (int j = 0; j < 8; j++) { float v = a[j]*a[j]; r8[j] = v; }
    for (int i = 8; i < 128; i += 8) {
      #pragma unroll
      for (int j = 0; j < 8; j++) { float v = a[i+j]*a[i+j]; r8[j] = r8[j] + v; }
    }
    zz_s[t] = ((r8[0]+r8[1]) + (r8[2]+r8[3])) + ((r8[4]+r8[5]) + (r8[6]+r8[7]));
  }
  __syncthreads();

  const int lane = t & 63, wv = t >> 6;
  float zzr[16];
  #pragma unroll
  for (int row = 0; row < 16; row++) zzr[row] = zz_s[row];

  float best[16]; int bid[16];
  #pragma unroll
  for (int row = 0; row < 16; row++) { best[row] = INFINITY; bid[row] = 0; }

  #pragma unroll 1
  for (int k = 0; k < 8; k++) {
    const int cg   = wv + (k << 4);        // 16 waves cover 128 groups of 64 codes
    const int code = (cg << 6) + lane;     // ascending in k for fixed lane
    const float* ep = cb + (size_t)code * 128;
    float r[16];
    #pragma unroll
    for (int row = 0; row < 16; row++) r[row] = 0.0f;
    #pragma unroll 1
    for (int d16 = 0; d16 < 8; d16++) {
      const float4 e0 = *(const float4*)(ep + d16*16 + 0);
      const float4 e1 = *(const float4*)(ep + d16*16 + 4);
      const float4 e2 = *(const float4*)(ep + d16*16 + 8);
      const float4 e3 = *(const float4*)(ep + d16*16 + 12);
      #pragma unroll
      for (int row = 0; row < 16; row++) {
        const float4 z0 = *(const float4*)(&z_s[row][d16*16 + 0]);   // uniform -> broadcast
        const float4 z1 = *(const float4*)(&z_s[row][d16*16 + 4]);
        const float4 z2 = *(const float4*)(&z_s[row][d16*16 + 8]);
        const float4 z3 = *(const float4*)(&z_s[row][d16*16 + 12]);
        float rr = r[row];
        // single dependent FMA chain, d ascending — identical to R3 (bit-exact)
        rr = fmaf(z0.x,e0.x,rr); rr = fmaf(z0.y,e0.y,rr); rr = fmaf(z0.z,e0.z,rr); rr = fmaf(z0.w,e0.w,rr);
        rr = fmaf(z1.x,e1.x,rr); rr = fmaf(z1.y,e1.y,rr); rr = fmaf(z1.z,e1.z,rr); rr = fmaf(z1.w,e1.w,rr);
        rr = fmaf(z2.x,e2.x,rr); rr = fmaf(z2.y,e2.y,rr); rr = fmaf(z2.z,e2.z,rr); rr = fmaf(z2.w,e2.w,rr);
        rr = fmaf(z3.x,e3.x,rr); rr = fmaf(z3.y,e3.y,rr); rr = fmaf(z3.z,e3.z,rr); rr = fmaf(z3.w,e3.w,rr);
        r[row] = rr;
      }
    }
    #pragma unroll
    for (int row = 0; row < 16; row++) {
      const float tt = fmaf(-2.0f, r[row], zzr[row]);  // fl32(zz - 2r), single rounding
      if (tt < best[row]) { best[row] = tt; bid[row] = code; }
    }
  }

  // cross-lane lex argmin per row (tie -> smaller index)
  #pragma unroll 1
  for (int row = 0; row < 16; row++) {
    float v = best[row]; int i = bid[row];
    #pragma unroll
    for (int m = 32; m; m >>= 1) {
      float v2 = __shfl_xor(v, m, 64);
      int   i2 = __shfl_xor(i, m, 64);
      if (v2 < v || (v2 == v && i2 < i)) { v = v2; i = i2; }
    }
    if (lane == 0) { redv[wv][row] = v; redi[wv][row] = i; }
  }
  __syncthreads();

  if (t < 16) {   // row t: reduce over 16 waves
    float v = redv[0][t]; int i = redi[0][t];
    #pragma unroll 1
    for (int w = 1; w < 16; w++) {
      float v2 = redv[w][t]; int i2 = redi[w][t];
      if (v2 < v || (v2 == v && i2 < i)) { v = v2; i = i2; }
    }
    win[t] = i;
    idx_ws[b0 + t] = i;
    out_idx_f[b0 + t] = (float)i;   // float out; exact for idx < 2^24
  }
  __syncthreads();

  // loss partial: sum (z - e_win)^2 over 16 rows (f64; threshold slack huge)
  double ls = 0.0;
  for (int p = t; p < 2048; p += 1024) {
    int r = p >> 7, d = p & 127;
    float diff = z_s[r][d] - cb[(size_t)win[r]*128 + d];
    ls = fma((double)diff, (double)diff, ls);
  }
  #pragma unroll
  for (int m = 32; m; m >>= 1) ls += __shfl_xor(ls, m, 64);
  if (lane == 0) wsum[wv] = ls;
  __syncthreads();
  if (t == 0) {
    double s = 0.0;
    for (int w = 0; w < 16; w++) s += wsum[w];
    lpart[blockIdx.x] = s;
  }
}

__global__ __launch_bounds__(256) void fin_kernel(const double* __restrict__ lpart,
                                                  float* __restrict__ out_loss)
{
  __shared__ double s[256];
  const int t = threadIdx.x;
  s[t] = lpart[t];
  __syncthreads();
  for (int off = 128; off; off >>= 1) {
    if (t < off) s[t] += s[t + off];
    __syncthreads();
  }
  if (t == 0) {
    float l = (float)(s[0] / (4096.0*128.0));
    out_loss[0] = l;   // codebook_loss
    out_loss[1] = l;   // commitment_loss (same value)
  }
}

// ===================== linear: x1[b,o] = cb[idx[b]] . lin_w[o] + lin_b[o] ====
__global__ __launch_bounds__(256) void linear_kernel(
    const float* __restrict__ cb, const int* __restrict__ idx,
    const float* __restrict__ lw, const float* __restrict__ lb,
    float* __restrict__ x1)
{
  __shared__ float As[64][65];
  __shared__ float Bs[64][65];
  __shared__ int idx_s[64];
  const int t  = threadIdx.x;
  const int b0 = blockIdx.x * 64, n0 = blockIdx.y * 64;
  if (t < 64) idx_s[t] = idx[b0 + t];
  float acc[4][4] = {{0.f}};
  const int tr = (t >> 4)*4, tc = (t & 15)*4;
  for (int d0 = 0; d0 < 128; d0 += 64) {
    __syncthreads();
    #pragma unroll
    for (int l = 0; l < 16; l++) {
      int flat = t + l*256;
      int r = flat >> 6, d = flat & 63;
      As[r][d] = cb[(size_t)idx_s[r]*128 + d0 + d];
      Bs[r][d] = lw[(size_t)(n0 + r)*128 + d0 + d];
    }
    __syncthreads();
    #pragma unroll 8
    for (int d = 0; d < 64; d++) {
      float a0 = As[tr+0][d], a1 = As[tr+1][d], a2 = As[tr+2][d], a3 = As[tr+3][d];
      float q0 = Bs[tc+0][d], q1 = Bs[tc+1][d], q2 = Bs[tc+2][d], q3 = Bs[tc+3][d];
      acc[0][0] = fmaf(a0,q0,acc[0][0]); acc[0][1] = fmaf(a0,q1,acc[0][1]);
      acc[0][2] = fmaf(a0,q2,acc[0][2]); acc[0][3] = fmaf(a0,q3,acc[0][3]);
      acc[1][0] = fmaf(a1,q0,acc[1][0]); acc[1][1] = fmaf(a1,q1,acc[1][1]);
      acc[1][2] = fmaf(a1,q2,acc[1][2]); acc[1][3] = fmaf(a1,q3,acc[1][3]);
      acc[2][0] = fmaf(a2,q0,acc[2][0]); acc[2][1] = fmaf(a2,q1,acc[2][1]);
      acc[2][2] = fmaf(a2,q2,acc[2][2]); acc[2][3] = fmaf(a2,q3,acc[2][3]);
      acc[3][0] = fmaf(a3,q0,acc[3][0]); acc[3][1] = fmaf(a3,q1,acc[3][1]);
      acc[3][2] = fmaf(a3,q2,acc[3][2]); acc[3][3] = fmaf(a3,q3,acc[3][3]);
    }
  }
  #pragma unroll
  for (int i = 0; i < 4; i++)
    #pragma unroll
    for (int j = 0; j < 4; j++)
      x1[(size_t)(b0 + tr + i)*3136 + n0 + tc + j] = acc[i][j] + lb[n0 + tc + j];
}

// === decoder_a: conv1 + conv2, 2 img/block, LOW-PRESSURE sequenced loops =====
// R9 (this session): unified-VGPR model — 14-wave blocks force a 128 total
// (arch+acc) budget/wave; the compiler splits ~64 arch + 64 acc and shuffles
// the overflow through v_accvgpr copies (R4: ~2/3 of VALU-busy was non-FMA).
// R7/R8 exceeded even 128 total -> scratch spill (FETCH 3.5GB / 122MB).
// Fix: keep R4's structure (weights once per i, 2 images) but re-sequence
// each i-iteration so PEAK live stays < ~60:
//  * conv1: per i: w -> {rowsA, FMA A} -> {rowsB, FMA B}, scoped row arrays.
//    Peak ~ 28 acc + 14 rows + 8 w.
//  * conv2: per i: w -> {cols 0..8, FMA x0..13} -> {cols 7..15, FMA x14..27},
//    scoped row arrays. Peak ~ 28 acc + 18 rows + 8 w. LDS reads 8->12/i.
// FMA order per output unchanged (i-ascending, same tap order) -> bit-identical.
// Tripwire: FETCH_SIZE ~34MB (no scratch), VGPR <= 64.
#define DA_T 896
#define B1_CS 260            // channel stride (floats); %32==4 avoids epilogue-write pile-up
#define IMG_FL (64*B1_CS)    // floats per image's halo-plane set
__global__ __attribute__((amdgpu_flat_work_group_size(DA_T, DA_T),
                          amdgpu_waves_per_eu(4, 4)))
void decoder_a(
    const float* __restrict__ x1,
    const float* __restrict__ w1, const float* __restrict__ b1,
    const float* __restrict__ w2, const float* __restrict__ b2,
    float* __restrict__ a2, int b_off, int n_img)
{
  extern __shared__ float B1s[];   // 2*IMG_FL = 33280 floats = 133120 B
  const int tid = threadIdx.x;
  const int b   = blockIdx.x;
  const int iA  = 2*b;                    // local image index (chunk buffer)
  const bool hasB = (iA + 1) < n_img;     // block-uniform
  const int gA  = b_off + iA;             // global image index

  for (int p = tid; p < 2*IMG_FL; p += DA_T) B1s[p] = 0.0f;
  __syncthreads();

  // ---- conv1: (64,7,7) -> (64,14,14), relu. item = (c=tid&63, y=tid>>6) ----
  // Per i: weights once; image A rows+FMA, then image B rows+FMA (scoped).
  {
    const int c = tid & 63, y = tid >> 6;
    const int ky0 = (y & 1) ? 0 : 1;
    const int iy0 = (y + 1 - ky0) >> 1;   // valid if <7
    const int iy1 = iy0 - 1;              // valid if >=0
    const bool v0 = (iy0 < 7), v1 = (iy1 >= 0);   // wave-uniform (y = wave idx)
    const float bias = b1[c];
    float accA[14], accB[14];
    #pragma unroll
    for (int x = 0; x < 14; x++) { accA[x] = bias; accB[x] = bias; }
    const float* ximA = x1 + (size_t)gA*3136;
    const float* ximB = hasB ? (ximA + 3136) : ximA;   // dup A when no B (stores guarded)
    #pragma unroll 1
    for (int i = 0; i < 64; i++) {
      const float* wp = w1 + (((i << 6) + c) << 4) + ky0*4;
      const float4 wA4 = *(const float4*)(wp);
      const float4 wB4 = *(const float4*)(wp + 8);
      const float wa[4] = {wA4.x, wA4.y, wA4.z, wA4.w};
      const float wb[4] = {wB4.x, wB4.y, wB4.z, wB4.w};
      // ---- image A: rows + FMA (row arrays scoped -> not live during B) ----
      {
        float r0[7], r1[7];
        if (v0) {
          const float* xr = ximA + i*49 + iy0*7;
          #pragma unroll
          for (int j = 0; j < 7; j++) r0[j] = xr[j];
        } else {
          #pragma unroll
          for (int j = 0; j < 7; j++) r0[j] = 0.0f;
        }
        if (v1) {
          const float* xr = ximA + i*49 + iy1*7;
          #pragma unroll
          for (int j = 0; j < 7; j++) r1[j] = xr[j];
        } else {
          #pragma unroll
          for (int j = 0; j < 7; j++) r1[j] = 0.0f;
        }
        #pragma unroll
        for (int x = 0; x < 14; x++) {
          const int kxs = (x & 1) ? 0 : 1;
          const int ix0 = (x + 1 - kxs) >> 1;
          const int ix1 = ix0 - 1;
          float s = accA[x];
          if (ix0 < 7)  { s = fmaf(r0[ix0], wa[kxs],   s); s = fmaf(r1[ix0], wb[kxs],   s); }
          if (ix1 >= 0) { s = fmaf(r0[ix1], wa[kxs+2], s); s = fmaf(r1[ix1], wb[kxs+2], s); }
          accA[x] = s;
        }
      }
      // ---- image B: rows + FMA ----
      {
        float r0[7], r1[7];
        if (v0) {
          const float* xr = ximB + i*49 + iy0*7;
          #pragma unroll
          for (int j = 0; j < 7; j++) r0[j] = xr[j];
        } else {
          #pragma unroll
          for (int j = 0; j < 7; j++) r0[j] = 0.0f;
        }
        if (v1) {
          const float* xr = ximB + i*49 + iy1*7;
          #pragma unroll
          for (int j = 0; j < 7; j++) r1[j] = xr[j];
        } else {
          #pragma unroll
          for (int j = 0; j < 7; j++) r1[j] = 0.0f;
        }
        #pragma unroll
        for (int x = 0; x < 14; x++) {
          const int kxs = (x & 1) ? 0 : 1;
          const int ix0 = (x + 1 - kxs) >> 1;
          const int ix1 = ix0 - 1;
          float s = accB[x];
          if (ix0 < 7)  { s = fmaf(r0[ix0], wa[kxs],   s); s = fmaf(r1[ix0], wb[kxs],   s); }
          if (ix1 >= 0) { s = fmaf(r0[ix1], wa[kxs+2], s); s = fmaf(r1[ix1], wb[kxs+2], s); }
          accB[x] = s;
        }
      }
    }
    // write interior of halo planes: row y+1, cols 1..14
    float* oA = &B1s[c*B1_CS + (y + 1)*16 + 1];
    float* oB = oA + IMG_FL;
    #pragma unroll
    for (int x = 0; x < 14; x++) oA[x] = fmaxf(accA[x], 0.0f);
    #pragma unroll
    for (int x = 0; x < 14; x++) oB[x] = fmaxf(accB[x], 0.0f);
  }
  __syncthreads();

  // ---- conv2: (64,14,14) -> (32,28,28), relu. item = (c=tid&31, y=tid>>5) ----
  // Sequential per-image phases; per i: weights once, then two x-chunks with
  // scoped row arrays (cols 0..8 -> x0..13; cols 7..15 -> x14..27).
  {
    const int c = tid & 31, y = tid >> 5;
    const int ky0 = (y & 1) ? 0 : 1;
    const int iy0 = (y + 1 - ky0) >> 1;     // 0..14
    const int row0 = iy0 + 1;               // halo row for ky0   (1..15)
    const int row1 = iy0;                   // halo row for ky0+2 (0..14)
    const float bias = b2[c];
    const int nimg = hasB ? 2 : 1;
    #pragma unroll 1
    for (int img = 0; img < nimg; img++) {
      const float* base   = &B1s[img*IMG_FL];
      const float* rbase0 = base + row0*16;
      const float* rbase1 = base + row1*16;
      float acc[28];
      #pragma unroll
      for (int x = 0; x < 28; x++) acc[x] = bias;
      #pragma unroll 1
      for (int i = 0; i < 64; i++) {
        const float* wp = w2 + (((i << 5) + c) << 4) + ky0*4;
        const float4 wA4 = *(const float4*)(wp);
        const float4 wB4 = *(const float4*)(wp + 8);
        const float wa[4] = {wA4.x, wA4.y, wA4.z, wA4.w};
        const float wb[4] = {wB4.x, wB4.y, wB4.z, wB4.w};
        const float* rp0 = rbase0 + i*B1_CS;
        const float* rp1 = rbase1 + i*B1_CS;
        // ---- chunk 1: halo cols 0..8 -> outputs x 0..13 ----
        {
          float r0[9], r1[9];
          {
            const float4 a4 = *(const float4*)(rp0 + 0);
            const float4 b4 = *(const float4*)(rp0 + 4);
            r0[0]=a4.x; r0[1]=a4.y; r0[2]=a4.z; r0[3]=a4.w;
            r0[4]=b4.x; r0[5]=b4.y; r0[6]=b4.z; r0[7]=b4.w; r0[8]=rp0[8];
            const float4 c4 = *(const float4*)(rp1 + 0);
            const float4 d4 = *(const float4*)(rp1 + 4);
            r1[0]=c4.x; r1[1]=c4.y; r1[2]=c4.z; r1[3]=c4.w;
            r1[4]=d4.x; r1[5]=d4.y; r1[6]=d4.z; r1[7]=d4.w; r1[8]=rp1[8];
          }
          #pragma unroll
          for (int x = 0; x < 14; x++) {
            const int kxs = (x & 1) ? 0 : 1;
            const int col = ((x + 1 - kxs) >> 1) + 1;   // 1..8
            float s = acc[x];
            s = fmaf(r0[col],   wa[kxs],   s);
            s = fmaf(r1[col],   wb[kxs],   s);
            s = fmaf(r0[col-1], wa[kxs+2], s);
            s = fmaf(r1[col-1], wb[kxs+2], s);
            acc[x] = s;
          }
        }
        // ---- chunk 2: halo cols 7..15 -> outputs x 14..27 ----
        {
          float r0[9], r1[9];   // r0[j] = col 7+j
          {
            r0[0]=rp0[7];
            const float4 a4 = *(const float4*)(rp0 + 8);
            const float4 b4 = *(const float4*)(rp0 + 12);
            r0[1]=a4.x; r0[2]=a4.y; r0[3]=a4.z; r0[4]=a4.w;
            r0[5]=b4.x; r0[6]=b4.y; r0[7]=b4.z; r0[8]=b4.w;
            r1[0]=rp1[7];
            const float4 c4 = *(const float4*)(rp1 + 8);
            const float4 d4 = *(const float4*)(rp1 + 12);
            r1[1]=c4.x; r1[2]=c4.y; r1[3]=c4.z; r1[4]=c4.w;
            r1[5]=d4.x; r1[6]=d4.y; r1[7]=d4.z; r1[8]=d4.w;
          }
          #pragma unroll
          for (int x = 14; x < 28; x++) {
            const int kxs = (x & 1) ? 0 : 1;
            const int col = ((x + 1 - kxs) >> 1) + 1;   // 8..15
            const int j = col - 7;                      // 1..8
            float s = acc[x];
            s = fmaf(r0[j],   wa[kxs],   s);
            s = fmaf(r1[j],   wb[kxs],   s);
            s = fmaf(r0[j-1], wa[kxs+2], s);
            s = fmaf(r1[j-1], wb[kxs+2], s);
            acc[x] = s;
          }
        }
      }
      // ---- epilogue: relu + store row (28 floats contiguous) ----
      float* st = a2 + (size_t)(iA + img)*25088 + c*784 + y*28;
      #pragma unroll
      for (int x = 0; x < 28; x++) acc[x] = fmaxf(acc[x], 0.0f);
      #pragma unroll
      for (int q = 0; q < 7; q++)
        *(float4*)(st + q*4) = make_float4(acc[q*4+0],acc[q*4+1],acc[q*4+2],acc[q*4+3]);
    }
  }
}

// ============ decoder_b: conv3 + bilinear resize 56->84 + tanh ==============
#define DB_T 896
__global__ __attribute__((amdgpu_flat_work_group_size(DB_T, DB_T)))
void decoder_b(
    const float* __restrict__ a2,
    const float* __restrict__ w3, const float* __restrict__ b3,
    float* __restrict__ out, int b_off)
{
  extern __shared__ float lds[];
  float* Cs  = lds;           // 25088 (a2 image, [c][y][x])
  float* Ds  = lds + 25088;   // 3136  (conv3 out, 56x56)
  float* W3s = lds + 28224;   // 512
  const int tid = threadIdx.x;
  const int b   = blockIdx.x;
  const int bg  = b + b_off;

  {
    const float4* src = (const float4*)(a2 + (size_t)b*25088);
    for (int p = tid; p < 6272; p += DB_T) ((float4*)Cs)[p] = src[p];
    for (int p = tid; p < 512; p += DB_T) W3s[p] = w3[p];
  }
  __syncthreads();

  if (tid < 784) {   // item = (y=tid/14 in 0..55, xq=tid%14), 4 px each
    const int y = tid / 14, xq = tid - y*14;
    const int x0 = xq * 4;
    const int ky0 = (y & 1) ? 0 : 1;
    const int iy0 = (y + 1 - ky0) >> 1;   // valid if <28
    const int iy1 = iy0 - 1;              // valid if >=0
    const bool v0 = (iy0 < 28), v1 = (iy1 >= 0);
    const int ixb = (x0 >> 1) - 1;        // input col for j=0
    float acc[4];
    const float bias = b3[0];
    #pragma unroll
    for (int x = 0; x < 4; x++) acc[x] = bias;
    #pragma unroll 1
    for (int i = 0; i < 32; i++) {
      const float* wr = &W3s[i*16 + ky0*4];
      float wa[4], wb[4];
      #pragma unroll
      for (int k = 0; k < 4; k++) { wa[k] = wr[k]; wb[k] = wr[8 + k]; }
      const float* Ci = &Cs[i*784];
      float r0[4], r1[4];
      #pragma unroll
      for (int j = 0; j < 4; j++) {
        const int ix = ixb + j;
        const bool vx = (ix >= 0) && (ix < 28);
        r0[j] = (v0 && vx) ? Ci[iy0*28 + ix] : 0.0f;
        r1[j] = (v1 && vx) ? Ci[iy1*28 + ix] : 0.0f;
      }
      #pragma unroll
      for (int xl = 0; xl < 4; xl++) {
        const int kxs = (xl & 1) ? 0 : 1;     // x0 even
        const int j = ((x0 + xl + 1 - kxs) >> 1) - ixb;   // 1..3
        float s = acc[xl];
        s = fmaf(r0[j],   wa[kxs],   s);
        s = fmaf(r1[j],   wb[kxs],   s);
        s = fmaf(r0[j-1], wa[kxs+2], s);
        s = fmaf(r1[j-1], wb[kxs+2], s);
        acc[xl] = s;
      }
    }
    *(float4*)(&Ds[y*56 + x0]) = make_float4(acc[0],acc[1],acc[2],acc[3]);
  }
  __syncthreads();

  // bilinear resize 56->84 (half-pixel, edge clamp == jax renorm) + tanh
  for (int p = tid; p < 84*84; p += DB_T) {
    const int oy = p / 84, ox = p - oy*84;
    const float sy = (oy + 0.5f)*(2.0f/3.0f) - 0.5f;
    const float sx = (ox + 0.5f)*(2.0f/3.0f) - 0.5f;
    const int y0 = (int)floorf(sy), x0i = (int)floorf(sx);
    const float fy = sy - (float)y0, fx = sx - (float)x0i;
    const int y0c = y0 < 0 ? 0 : y0, y1c = (y0 + 1 > 55) ? 55 : (y0 + 1);
    const int x0c = x0i < 0 ? 0 : x0i, x1c = (x0i + 1 > 55) ? 55 : (x0i + 1);
    const float v00 = Ds[y0c*56 + x0c], v01 = Ds[y0c*56 + x1c];
    const float v10 = Ds[y1c*56 + x0c], v11 = Ds[y1c*56 + x1c];
    const float v = (v00*(1.0f - fx) + v01*fx)*(1.0f - fy)
                  + (v10*(1.0f - fx) + v11*fx)*fy;
    out[(size_t)bg*7056 + p] = tanhf(v);
  }
}

// ================================ launch ====================================
extern "C" void kernel_launch(void* const* d_in, const int* in_sizes, int n_in,
                              void* d_out, int out_size, void* d_ws, size_t ws_size,
                              hipStream_t stream) {
  (void)in_sizes; (void)n_in; (void)out_size;
  const float* z  = (const float*)d_in[0];
  const float* cb = (const float*)d_in[1];
  const float* lw = (const float*)d_in[2];
  const float* lb = (const float*)d_in[3];
  const float* w1 = (const float*)d_in[4];
  const float* b1 = (const float*)d_in[5];
  const float* w2 = (const float*)d_in[6];
  const float* b2 = (const float*)d_in[7];
  const float* w3 = (const float*)d_in[8];
  const float* b3 = (const float*)d_in[9];

  float* out      = (float*)d_out;
  float* out_idx  = out + RECON_N;          // 4096 indices as float
  float* out_loss = out + RECON_N + 4096;   // 2 losses

  char*   ws     = (char*)d_ws;
  double* lpart  = (double*)ws;             // 256 doubles
  int*    idx_ws = (int*)(ws + 4096);       // 4096 ints
  float*  x1     = (float*)(ws + 32768);    // 4096*3136 floats (51.4 MB)
  const size_t a2_off = 32768 + (size_t)4096*3136*4;
  float*  a2     = (float*)(ws + a2_off);   // up to 4096*25088 floats (411 MB)

  // chunk the decoder if ws is too small for the full a2 buffer
  long long avail = (long long)ws_size - (long long)a2_off;
  int cap = (int)(avail / (25088*4));
  if (cap > 4096) cap = 4096;
  if (cap < 1) cap = 1;
  if (cap >= 2) cap &= ~1;   // even chunks so decoder_a blocks own full pairs

  vq_kernel<<<256, 1024, 0, stream>>>(z, cb, idx_ws, out_idx, lpart);
  fin_kernel<<<1, 256, 0, stream>>>(lpart, out_loss);
  linear_kernel<<<dim3(64, 49), 256, 0, stream>>>(cb, idx_ws, lw, lb, x1);

  const int da_lds = 2*IMG_FL*4;           // 133120 B (2 images)
  const int db_lds = (25088+3136+512)*4;   // 114944 B
  hipFuncSetAttribute((const void*)decoder_a,
                      hipFuncAttributeMaxDynamicSharedMemorySize, da_lds);
  hipFuncSetAttribute((const void*)decoder_b,
                      hipFuncAttributeMaxDynamicSharedMemorySize, db_lds);
  for (int b0 = 0; b0 < B_SZ; b0 += cap) {
    const int n = (B_SZ - b0 < cap) ? (B_SZ - b0) : cap;
    decoder_a<<<(n + 1)/2, DA_T, da_lds, stream>>>(x1, w1, b1, w2, b2, a2, b0, n);
    decoder_b<<<n, DB_T, db_lds, stream>>>(a2, w3, b3, out, b0);
  }
}

// Round 10
// 2154.450 us; speedup vs baseline: 2.1059x; 1.0574x over previous
//
#include <hip/hip_runtime.h>
#include <math.h>

// Problem constants
#define B_SZ    4096
#define D_DIM   128
#define K_CODES 8192
#define RECON_N (4096*84*84)   // 28901376

// ============================ VQ argmin + losses ============================
// Exact numpy-f32 semantics (verified R2/R3): d2q = fl32(zz - 2r), r = sequential
// f32 FMA chain over d ascending, zz = numpy pairwise-8. Ties -> lowest index.
__global__ __attribute__((amdgpu_flat_work_group_size(1024,1024),
                          amdgpu_waves_per_eu(4,8)))
void vq_kernel(
    const float* __restrict__ z, const float* __restrict__ cb,
    int* __restrict__ idx_ws, float* __restrict__ out_idx_f,
    double* __restrict__ lpart)
{
  __shared__ float z_s[16][128];
  __shared__ float zz_s[16];
  __shared__ float redv[16][16];   // [wave][row]
  __shared__ int   redi[16][16];
  __shared__ int   win[16];
  __shared__ double wsum[16];
  const int t  = threadIdx.x;
  const int b0 = blockIdx.x * 16;

  for (int p = t; p < 2048; p += 1024) z_s[p >> 7][p & 127] = z[(size_t)b0*128 + p];
  __syncthreads();

  // numpy pairwise-8 emulation of (z*z).sum(axis=1); separate mul/add roundings
  if (t < 16) {
    #pragma clang fp contract(off)
    const float* a = z_s[t];
    float r8[8];
    #pragma unroll
    for (int j = 0; j < 8; j++) { float v = a[j]*a[j]; r8[j] = v; }
    for (int i = 8; i < 128; i += 8) {
      #pragma unroll
      for (int j = 0; j < 8; j++) { float v = a[i+j]*a[i+j]; r8[j] = r8[j] + v; }
    }
    zz_s[t] = ((r8[0]+r8[1]) + (r8[2]+r8[3])) + ((r8[4]+r8[5]) + (r8[6]+r8[7]));
  }
  __syncthreads();

  const int lane = t & 63, wv = t >> 6;
  float zzr[16];
  #pragma unroll
  for (int row = 0; row < 16; row++) zzr[row] = zz_s[row];

  float best[16]; int bid[16];
  #pragma unroll
  for (int row = 0; row < 16; row++) { best[row] = INFINITY; bid[row] = 0; }

  #pragma unroll 1
  for (int k = 0; k < 8; k++) {
    const int cg   = wv + (k << 4);        // 16 waves cover 128 groups of 64 codes
    const int code = (cg << 6) + lane;     // ascending in k for fixed lane
    const float* ep = cb + (size_t)code * 128;
    float r[16];
    #pragma unroll
    for (int row = 0; row < 16; row++) r[row] = 0.0f;
    #pragma unroll 1
    for (int d16 = 0; d16 < 8; d16++) {
      const float4 e0 = *(const float4*)(ep + d16*16 + 0);
      const float4 e1 = *(const float4*)(ep + d16*16 + 4);
      const float4 e2 = *(const float4*)(ep + d16*16 + 8);
      const float4 e3 = *(const float4*)(ep + d16*16 + 12);
      #pragma unroll
      for (int row = 0; row < 16; row++) {
        const float4 z0 = *(const float4*)(&z_s[row][d16*16 + 0]);   // uniform -> broadcast
        const float4 z1 = *(const float4*)(&z_s[row][d16*16 + 4]);
        const float4 z2 = *(const float4*)(&z_s[row][d16*16 + 8]);
        const float4 z3 = *(const float4*)(&z_s[row][d16*16 + 12]);
        float rr = r[row];
        // single dependent FMA chain, d ascending — identical to R3 (bit-exact)
        rr = fmaf(z0.x,e0.x,rr); rr = fmaf(z0.y,e0.y,rr); rr = fmaf(z0.z,e0.z,rr); rr = fmaf(z0.w,e0.w,rr);
        rr = fmaf(z1.x,e1.x,rr); rr = fmaf(z1.y,e1.y,rr); rr = fmaf(z1.z,e1.z,rr); rr = fmaf(z1.w,e1.w,rr);
        rr = fmaf(z2.x,e2.x,rr); rr = fmaf(z2.y,e2.y,rr); rr = fmaf(z2.z,e2.z,rr); rr = fmaf(z2.w,e2.w,rr);
        rr = fmaf(z3.x,e3.x,rr); rr = fmaf(z3.y,e3.y,rr); rr = fmaf(z3.z,e3.z,rr); rr = fmaf(z3.w,e3.w,rr);
        r[row] = rr;
      }
    }
    #pragma unroll
    for (int row = 0; row < 16; row++) {
      const float tt = fmaf(-2.0f, r[row], zzr[row]);  // fl32(zz - 2r), single rounding
      if (tt < best[row]) { best[row] = tt; bid[row] = code; }
    }
  }

  // cross-lane lex argmin per row (tie -> smaller index)
  #pragma unroll 1
  for (int row = 0; row < 16; row++) {
    float v = best[row]; int i = bid[row];
    #pragma unroll
    for (int m = 32; m; m >>= 1) {
      float v2 = __shfl_xor(v, m, 64);
      int   i2 = __shfl_xor(i, m, 64);
      if (v2 < v || (v2 == v && i2 < i)) { v = v2; i = i2; }
    }
    if (lane == 0) { redv[wv][row] = v; redi[wv][row] = i; }
  }
  __syncthreads();

  if (t < 16) {   // row t: reduce over 16 waves
    float v = redv[0][t]; int i = redi[0][t];
    #pragma unroll 1
    for (int w = 1; w < 16; w++) {
      float v2 = redv[w][t]; int i2 = redi[w][t];
      if (v2 < v || (v2 == v && i2 < i)) { v = v2; i = i2; }
    }
    win[t] = i;
    idx_ws[b0 + t] = i;
    out_idx_f[b0 + t] = (float)i;   // float out; exact for idx < 2^24
  }
  __syncthreads();

  // loss partial: sum (z - e_win)^2 over 16 rows (f64; threshold slack huge)
  double ls = 0.0;
  for (int p = t; p < 2048; p += 1024) {
    int r = p >> 7, d = p & 127;
    float diff = z_s[r][d] - cb[(size_t)win[r]*128 + d];
    ls = fma((double)diff, (double)diff, ls);
  }
  #pragma unroll
  for (int m = 32; m; m >>= 1) ls += __shfl_xor(ls, m, 64);
  if (lane == 0) wsum[wv] = ls;
  __syncthreads();
  if (t == 0) {
    double s = 0.0;
    for (int w = 0; w < 16; w++) s += wsum[w];
    lpart[blockIdx.x] = s;
  }
}

__global__ __launch_bounds__(256) void fin_kernel(const double* __restrict__ lpart,
                                                  float* __restrict__ out_loss)
{
  __shared__ double s[256];
  const int t = threadIdx.x;
  s[t] = lpart[t];
  __syncthreads();
  for (int off = 128; off; off >>= 1) {
    if (t < off) s[t] += s[t + off];
    __syncthreads();
  }
  if (t == 0) {
    float l = (float)(s[0] / (4096.0*128.0));
    out_loss[0] = l;   // codebook_loss
    out_loss[1] = l;   // commitment_loss (same value)
  }
}

// ===================== linear: x1[b,o] = cb[idx[b]] . lin_w[o] + lin_b[o] ====
__global__ __launch_bounds__(256) void linear_kernel(
    const float* __restrict__ cb, const int* __restrict__ idx,
    const float* __restrict__ lw, const float* __restrict__ lb,
    float* __restrict__ x1)
{
  __shared__ float As[64][65];
  __shared__ float Bs[64][65];
  __shared__ int idx_s[64];
  const int t  = threadIdx.x;
  const int b0 = blockIdx.x * 64, n0 = blockIdx.y * 64;
  if (t < 64) idx_s[t] = idx[b0 + t];
  float acc[4][4] = {{0.f}};
  const int tr = (t >> 4)*4, tc = (t & 15)*4;
  for (int d0 = 0; d0 < 128; d0 += 64) {
    __syncthreads();
    #pragma unroll
    for (int l = 0; l < 16; l++) {
      int flat = t + l*256;
      int r = flat >> 6, d = flat & 63;
      As[r][d] = cb[(size_t)idx_s[r]*128 + d0 + d];
      Bs[r][d] = lw[(size_t)(n0 + r)*128 + d0 + d];
    }
    __syncthreads();
    #pragma unroll 8
    for (int d = 0; d < 64; d++) {
      float a0 = As[tr+0][d], a1 = As[tr+1][d], a2 = As[tr+2][d], a3 = As[tr+3][d];
      float q0 = Bs[tc+0][d], q1 = Bs[tc+1][d], q2 = Bs[tc+2][d], q3 = Bs[tc+3][d];
      acc[0][0] = fmaf(a0,q0,acc[0][0]); acc[0][1] = fmaf(a0,q1,acc[0][1]);
      acc[0][2] = fmaf(a0,q2,acc[0][2]); acc[0][3] = fmaf(a0,q3,acc[0][3]);
      acc[1][0] = fmaf(a1,q0,acc[1][0]); acc[1][1] = fmaf(a1,q1,acc[1][1]);
      acc[1][2] = fmaf(a1,q2,acc[1][2]); acc[1][3] = fmaf(a1,q3,acc[1][3]);
      acc[2][0] = fmaf(a2,q0,acc[2][0]); acc[2][1] = fmaf(a2,q1,acc[2][1]);
      acc[2][2] = fmaf(a2,q2,acc[2][2]); acc[2][3] = fmaf(a2,q3,acc[2][3]);
      acc[3][0] = fmaf(a3,q0,acc[3][0]); acc[3][1] = fmaf(a3,q1,acc[3][1]);
      acc[3][2] = fmaf(a3,q2,acc[3][2]); acc[3][3] = fmaf(a3,q3,acc[3][3]);
    }
  }
  #pragma unroll
  for (int i = 0; i < 4; i++)
    #pragma unroll
    for (int j = 0; j < 4; j++)
      x1[(size_t)(b0 + tr + i)*3136 + n0 + tc + j] = acc[i][j] + lb[n0 + tc + j];
}

// ===================== decoder_a: conv1 + conv2, TWO images per block ========
// R10 (this session): R4 structure restored verbatim (best verified point:
// decoder_a 1517us) — every other lever tried since was neutral or negative
// (occupancy: LDS size / block shape both falsified; deep pipelining / weight
// dbuf: spills past ~80 live values; pressure re-sequencing: net negative).
// Two strictly-positive micro-cuts on top of R4:
//  * zero-fill shrunk 8x: only halo rows 0/15 per plane (4096 vs 33280 floats);
//    halo cols 0/15 are written by the conv1 epilogue below.
//  * conv1 epilogue: 4x ds_write_b128 full-row (cols 0..15, zero ends) per
//    image instead of 14 scalar ds_write (16B-aligned: c*260 % 4 == 0).
// Values and FMA chains bit-identical to R4.
#define DA_T 896
#define B1_CS 260            // channel stride (floats); %32==4 keeps conflicts mild
#define IMG_FL (64*B1_CS)    // floats per image's halo-plane set
__global__ __attribute__((amdgpu_flat_work_group_size(DA_T, DA_T),
                          amdgpu_waves_per_eu(4, 4)))
void decoder_a(
    const float* __restrict__ x1,
    const float* __restrict__ w1, const float* __restrict__ b1,
    const float* __restrict__ w2, const float* __restrict__ b2,
    float* __restrict__ a2, int b_off, int n_img)
{
  extern __shared__ float B1s[];   // 2*IMG_FL = 33280 floats = 133120 B
  const int tid = threadIdx.x;
  const int b   = blockIdx.x;
  const int iA  = 2*b;                    // local image index (chunk buffer)
  const bool hasB = (iA + 1) < n_img;     // block-uniform
  const int gA  = b_off + iA;             // global image index

  // zero only halo rows 0 and 15 of each of the 128 planes (2 img x 64 ch)
  for (int p = tid; p < 128*2*16; p += DA_T) {
    const int pl  = p >> 5;              // plane 0..127
    const int row = ((p >> 4) & 1) * 15; // 0 or 15
    const int col = p & 15;
    const int img = pl >> 6, c = pl & 63;
    B1s[img*IMG_FL + c*B1_CS + row*16 + col] = 0.0f;
  }
  __syncthreads();

  // ---- conv1: (64,7,7) -> (64,14,14), relu. item = (c=tid&63, y=tid>>6) ----
  {
    const int c = tid & 63, y = tid >> 6;
    const int ky0 = (y & 1) ? 0 : 1;
    const int iy0 = (y + 1 - ky0) >> 1;   // valid if <7
    const int iy1 = iy0 - 1;              // valid if >=0
    const bool v0 = (iy0 < 7), v1 = (iy1 >= 0);   // wave-uniform (y = wave idx)
    const float bias = b1[c];
    float accA[14], accB[14];
    #pragma unroll
    for (int x = 0; x < 14; x++) { accA[x] = bias; accB[x] = bias; }
    const float* ximA = x1 + (size_t)gA*3136;
    const float* ximB = hasB ? (ximA + 3136) : ximA;   // dup A when no B (stores guarded)
    #pragma unroll 1
    for (int i = 0; i < 64; i++) {
      const float* wp = w1 + (((i << 6) + c) << 4) + ky0*4;
      const float4 wA4 = *(const float4*)(wp);
      const float4 wB4 = *(const float4*)(wp + 8);
      const float wa[4] = {wA4.x, wA4.y, wA4.z, wA4.w};
      const float wb[4] = {wB4.x, wB4.y, wB4.z, wB4.w};
      float r0A[7], r1A[7], r0B[7], r1B[7];
      if (v0) {
        const float* xr = ximA + i*49 + iy0*7;
        const float* xs = ximB + i*49 + iy0*7;
        #pragma unroll
        for (int j = 0; j < 7; j++) { r0A[j] = xr[j]; r0B[j] = xs[j]; }
      } else {
        #pragma unroll
        for (int j = 0; j < 7; j++) { r0A[j] = 0.0f; r0B[j] = 0.0f; }
      }
      if (v1) {
        const float* xr = ximA + i*49 + iy1*7;
        const float* xs = ximB + i*49 + iy1*7;
        #pragma unroll
        for (int j = 0; j < 7; j++) { r1A[j] = xr[j]; r1B[j] = xs[j]; }
      } else {
        #pragma unroll
        for (int j = 0; j < 7; j++) { r1A[j] = 0.0f; r1B[j] = 0.0f; }
      }
      #pragma unroll
      for (int x = 0; x < 14; x++) {
        const int kxs = (x & 1) ? 0 : 1;
        const int ix0 = (x + 1 - kxs) >> 1;
        const int ix1 = ix0 - 1;
        float s = accA[x];
        if (ix0 < 7)  { s = fmaf(r0A[ix0], wa[kxs],   s); s = fmaf(r1A[ix0], wb[kxs],   s); }
        if (ix1 >= 0) { s = fmaf(r0A[ix1], wa[kxs+2], s); s = fmaf(r1A[ix1], wb[kxs+2], s); }
        accA[x] = s;
      }
      #pragma unroll
      for (int x = 0; x < 14; x++) {
        const int kxs = (x & 1) ? 0 : 1;
        const int ix0 = (x + 1 - kxs) >> 1;
        const int ix1 = ix0 - 1;
        float s = accB[x];
        if (ix0 < 7)  { s = fmaf(r0B[ix0], wa[kxs],   s); s = fmaf(r1B[ix0], wb[kxs],   s); }
        if (ix1 >= 0) { s = fmaf(r0B[ix1], wa[kxs+2], s); s = fmaf(r1B[ix1], wb[kxs+2], s); }
        accB[x] = s;
      }
    }
    // write full halo rows y+1 (cols 0..15, zero ends) as 4x b128 per image
    {
      float* o = &B1s[c*B1_CS + (y + 1)*16];
      #pragma unroll
      for (int x = 0; x < 14; x++) accA[x] = fmaxf(accA[x], 0.0f);
      *(float4*)(o + 0)  = make_float4(0.0f,     accA[0],  accA[1],  accA[2]);
      *(float4*)(o + 4)  = make_float4(accA[3],  accA[4],  accA[5],  accA[6]);
      *(float4*)(o + 8)  = make_float4(accA[7],  accA[8],  accA[9],  accA[10]);
      *(float4*)(o + 12) = make_float4(accA[11], accA[12], accA[13], 0.0f);
    }
    {
      float* o = &B1s[IMG_FL + c*B1_CS + (y + 1)*16];
      #pragma unroll
      for (int x = 0; x < 14; x++) accB[x] = fmaxf(accB[x], 0.0f);
      *(float4*)(o + 0)  = make_float4(0.0f,     accB[0],  accB[1],  accB[2]);
      *(float4*)(o + 4)  = make_float4(accB[3],  accB[4],  accB[5],  accB[6]);
      *(float4*)(o + 8)  = make_float4(accB[7],  accB[8],  accB[9],  accB[10]);
      *(float4*)(o + 12) = make_float4(accB[11], accB[12], accB[13], 0.0f);
    }
  }
  __syncthreads();

  // ---- conv2: (64,14,14) -> (32,28,28), relu. item = (c=tid&31, y=tid>>5) ----
  // Per-image sequential phases; full 16-float LDS rows, b128 only. (R4 form)
  {
    const int c = tid & 31, y = tid >> 5;
    const int ky0 = (y & 1) ? 0 : 1;
    const int iy0 = (y + 1 - ky0) >> 1;     // 0..14
    const int row0 = iy0 + 1;               // halo row for ky0   (1..15)
    const int row1 = iy0;                   // halo row for ky0+2 (0..14)
    const float bias = b2[c];
    const int nimg = hasB ? 2 : 1;
    #pragma unroll 1
    for (int img = 0; img < nimg; img++) {
      const float* base = &B1s[img*IMG_FL];
      float acc[28];
      #pragma unroll
      for (int x = 0; x < 28; x++) acc[x] = bias;
      #pragma unroll 1
      for (int i = 0; i < 64; i++) {
        const float* wp = w2 + (((i << 5) + c) << 4) + ky0*4;
        const float4 wA4 = *(const float4*)(wp);
        const float4 wB4 = *(const float4*)(wp + 8);
        const float wa[4] = {wA4.x, wA4.y, wA4.z, wA4.w};
        const float wb[4] = {wB4.x, wB4.y, wB4.z, wB4.w};
        const float* rp0 = base + i*B1_CS + row0*16;
        const float* rp1 = base + i*B1_CS + row1*16;
        float r0[16], r1[16];
        #pragma unroll
        for (int q = 0; q < 4; q++) {
          const float4 a4 = *(const float4*)(rp0 + q*4);
          r0[q*4+0]=a4.x; r0[q*4+1]=a4.y; r0[q*4+2]=a4.z; r0[q*4+3]=a4.w;
        }
        #pragma unroll
        for (int q = 0; q < 4; q++) {
          const float4 a4 = *(const float4*)(rp1 + q*4);
          r1[q*4+0]=a4.x; r1[q*4+1]=a4.y; r1[q*4+2]=a4.z; r1[q*4+3]=a4.w;
        }
        #pragma unroll
        for (int x = 0; x < 28; x++) {
          const int kxs = (x & 1) ? 0 : 1;
          const int col = ((x + 1 - kxs) >> 1) + 1;   // 1..15
          float s = acc[x];
          s = fmaf(r0[col],   wa[kxs],   s);
          s = fmaf(r1[col],   wb[kxs],   s);
          s = fmaf(r0[col-1], wa[kxs+2], s);
          s = fmaf(r1[col-1], wb[kxs+2], s);
          acc[x] = s;
        }
      }
      // ---- epilogue: relu + store row (28 floats contiguous) ----
      float* st = a2 + (size_t)(iA + img)*25088 + c*784 + y*28;
      #pragma unroll
      for (int x = 0; x < 28; x++) acc[x] = fmaxf(acc[x], 0.0f);
      #pragma unroll
      for (int q = 0; q < 7; q++)
        *(float4*)(st + q*4) = make_float4(acc[q*4+0],acc[q*4+1],acc[q*4+2],acc[q*4+3]);
    }
  }
}

// ============ decoder_b: conv3 + bilinear resize 56->84 + tanh ==============
#define DB_T 896
__global__ __attribute__((amdgpu_flat_work_group_size(DB_T, DB_T)))
void decoder_b(
    const float* __restrict__ a2,
    const float* __restrict__ w3, const float* __restrict__ b3,
    float* __restrict__ out, int b_off)
{
  extern __shared__ float lds[];
  float* Cs  = lds;           // 25088 (a2 image, [c][y][x])
  float* Ds  = lds + 25088;   // 3136  (conv3 out, 56x56)
  float* W3s = lds + 28224;   // 512
  const int tid = threadIdx.x;
  const int b   = blockIdx.x;
  const int bg  = b + b_off;

  {
    const float4* src = (const float4*)(a2 + (size_t)b*25088);
    for (int p = tid; p < 6272; p += DB_T) ((float4*)Cs)[p] = src[p];
    for (int p = tid; p < 512; p += DB_T) W3s[p] = w3[p];
  }
  __syncthreads();

  if (tid < 784) {   // item = (y=tid/14 in 0..55, xq=tid%14), 4 px each
    const int y = tid / 14, xq = tid - y*14;
    const int x0 = xq * 4;
    const int ky0 = (y & 1) ? 0 : 1;
    const int iy0 = (y + 1 - ky0) >> 1;   // valid if <28
    const int iy1 = iy0 - 1;              // valid if >=0
    const bool v0 = (iy0 < 28), v1 = (iy1 >= 0);
    const int ixb = (x0 >> 1) - 1;        // input col for j=0
    float acc[4];
    const float bias = b3[0];
    #pragma unroll
    for (int x = 0; x < 4; x++) acc[x] = bias;
    #pragma unroll 1
    for (int i = 0; i < 32; i++) {
      const float* wr = &W3s[i*16 + ky0*4];
      float wa[4], wb[4];
      #pragma unroll
      for (int k = 0; k < 4; k++) { wa[k] = wr[k]; wb[k] = wr[8 + k]; }
      const float* Ci = &Cs[i*784];
      float r0[4], r1[4];
      #pragma unroll
      for (int j = 0; j < 4; j++) {
        const int ix = ixb + j;
        const bool vx = (ix >= 0) && (ix < 28);
        r0[j] = (v0 && vx) ? Ci[iy0*28 + ix] : 0.0f;
        r1[j] = (v1 && vx) ? Ci[iy1*28 + ix] : 0.0f;
      }
      #pragma unroll
      for (int xl = 0; xl < 4; xl++) {
        const int kxs = (xl & 1) ? 0 : 1;     // x0 even
        const int j = ((x0 + xl + 1 - kxs) >> 1) - ixb;   // 1..3
        float s = acc[xl];
        s = fmaf(r0[j],   wa[kxs],   s);
        s = fmaf(r1[j],   wb[kxs],   s);
        s = fmaf(r0[j-1], wa[kxs+2], s);
        s = fmaf(r1[j-1], wb[kxs+2], s);
        acc[xl] = s;
      }
    }
    *(float4*)(&Ds[y*56 + x0]) = make_float4(acc[0],acc[1],acc[2],acc[3]);
  }
  __syncthreads();

  // bilinear resize 56->84 (half-pixel, edge clamp == jax renorm) + tanh
  for (int p = tid; p < 84*84; p += DB_T) {
    const int oy = p / 84, ox = p - oy*84;
    const float sy = (oy + 0.5f)*(2.0f/3.0f) - 0.5f;
    const float sx = (ox + 0.5f)*(2.0f/3.0f) - 0.5f;
    const int y0 = (int)floorf(sy), x0i = (int)floorf(sx);
    const float fy = sy - (float)y0, fx = sx - (float)x0i;
    const int y0c = y0 < 0 ? 0 : y0, y1c = (y0 + 1 > 55) ? 55 : (y0 + 1);
    const int x0c = x0i < 0 ? 0 : x0i, x1c = (x0i + 1 > 55) ? 55 : (x0i + 1);
    const float v00 = Ds[y0c*56 + x0c], v01 = Ds[y0c*56 + x1c];
    const float v10 = Ds[y1c*56 + x0c], v11 = Ds[y1c*56 + x1c];
    const float v = (v00*(1.0f - fx) + v01*fx)*(1.0f - fy)
                  + (v10*(1.0f - fx) + v11*fx)*fy;
    out[(size_t)bg*7056 + p] = tanhf(v);
  }
}

// ================================ launch ====================================
extern "C" void kernel_launch(void* const* d_in, const int* in_sizes, int n_in,
                              void* d_out, int out_size, void* d_ws, size_t ws_size,
                              hipStream_t stream) {
  (void)in_sizes; (void)n_in; (void)out_size;
  const float* z  = (const float*)d_in[0];
  const float* cb = (const float*)d_in[1];
  const float* lw = (const float*)d_in[2];
  const float* lb = (const float*)d_in[3];
  const float* w1 = (const float*)d_in[4];
  const float* b1 = (const float*)d_in[5];
  const float* w2 = (const float*)d_in[6];
  const float* b2 = (const float*)d_in[7];
  const float* w3 = (const float*)d_in[8];
  const float* b3 = (const float*)d_in[9];

  float* out      = (float*)d_out;
  float* out_idx  = out + RECON_N;          // 4096 indices as float
  float* out_loss = out + RECON_N + 4096;   // 2 losses

  char*   ws     = (char*)d_ws;
  double* lpart  = (double*)ws;             // 256 doubles
  int*    idx_ws = (int*)(ws + 4096);       // 4096 ints
  float*  x1     = (float*)(ws + 32768);    // 4096*3136 floats (51.4 MB)
  const size_t a2_off = 32768 + (size_t)4096*3136*4;
  float*  a2     = (float*)(ws + a2_off);   // up to 4096*25088 floats (411 MB)

  // chunk the decoder if ws is too small for the full a2 buffer
  long long avail = (long long)ws_size - (long long)a2_off;
  int cap = (int)(avail / (25088*4));
  if (cap > 4096) cap = 4096;
  if (cap < 1) cap = 1;
  if (cap >= 2) cap &= ~1;   // even chunks so decoder_a blocks own full pairs

  vq_kernel<<<256, 1024, 0, stream>>>(z, cb, idx_ws, out_idx, lpart);
  fin_kernel<<<1, 256, 0, stream>>>(lpart, out_loss);
  linear_kernel<<<dim3(64, 49), 256, 0, stream>>>(cb, idx_ws, lw, lb, x1);

  const int da_lds = 2*IMG_FL*4;           // 133120 B (2 images)
  const int db_lds = (25088+3136+512)*4;   // 114944 B
  hipFuncSetAttribute((const void*)decoder_a,
                      hipFuncAttributeMaxDynamicSharedMemorySize, da_lds);
  hipFuncSetAttribute((const void*)decoder_b,
                      hipFuncAttributeMaxDynamicSharedMemorySize, db_lds);
  for (int b0 = 0; b0 < B_SZ; b0 += cap) {
    const int n = (B_SZ - b0 < cap) ? (B_SZ - b0) : cap;
    decoder_a<<<(n + 1)/2, DA_T, da_lds, stream>>>(x1, w1, b1, w2, b2, a2, b0, n);
    decoder_b<<<n, DB_T, db_lds, stream>>>(a2, w3, b3, out, b0);
  }
}